// Round 1
// baseline (837.091 us; speedup 1.0000x reference)
//
#include <hip/hip_runtime.h>
#include <math.h>

#define N_AGENTS 8192
#define HIDDEN   256
#define MSG      128
#define KEYD     64
#define CSPLIT   8

typedef __attribute__((ext_vector_type(8))) short short8_t;
typedef __attribute__((ext_vector_type(4))) short short4_t;
typedef __attribute__((ext_vector_type(4))) float float4_t;

__device__ __forceinline__ short f2bf(float x) {
    unsigned u = __float_as_uint(x);
    unsigned r = (u + 0x7fffu + ((u >> 16) & 1u)) >> 16;
    return (short)r;
}
__device__ __forceinline__ float bf2f(short b) {
    return __uint_as_float(((unsigned)(unsigned short)b) << 16);
}

// ---------------- Kernel A: projections -> bf16 side buffers ------------------
__global__ __launch_bounds__(256) void proj_kernel(
    const float* __restrict__ h,
    const float* __restrict__ Wm, const float* __restrict__ bm,
    const float* __restrict__ Wk, const float* __restrict__ bk,
    const float* __restrict__ Wq, const float* __restrict__ bq,
    short* __restrict__ msgTb,
    short* __restrict__ qh, short* __restrict__ ql,
    short* __restrict__ kh, short* __restrict__ kl)
{
    const int R = 16;
    __shared__ float hs[R][HIDDEN];
    int i0 = blockIdx.x * R;
    int t = threadIdx.x;  // 256

    for (int l = t; l < R * HIDDEN; l += 256) {
        int r = l >> 8, k = l & 255;
        hs[r][k] = h[(size_t)(i0 + r) * HIDDEN + k];
    }
    __syncthreads();

    int j = t;
    const float* Wp; int stride, col; float bias;
    if (j < 128)      { Wp = Wm; stride = 128; col = j;       bias = bm[col]; }
    else if (j < 192) { Wp = Wk; stride = 64;  col = j - 128; bias = bk[col]; }
    else              { Wp = Wq; stride = 64;  col = j - 192; bias = bq[col]; }

    float acc[R];
#pragma unroll
    for (int r = 0; r < R; r++) acc[r] = 0.f;

    for (int k = 0; k < HIDDEN; k++) {
        float w = Wp[(size_t)k * stride + col];
#pragma unroll
        for (int r = 0; r < R; r++) acc[r] += hs[r][k] * w;
    }

    if (j < 128) {
#pragma unroll
        for (int r = 0; r < R; r++)
            msgTb[(size_t)col * N_AGENTS + i0 + r] = f2bf(acc[r] + bias);
    } else if (j < 192) {
#pragma unroll
        for (int r = 0; r < R; r++) {
            float v = acc[r] + bias;
            short hi = f2bf(v);
            short lo = f2bf(v - bf2f(hi));
            kh[(size_t)(i0 + r) * KEYD + col] = hi;
            kl[(size_t)(i0 + r) * KEYD + col] = lo;
        }
    } else {
#pragma unroll
        for (int r = 0; r < R; r++) {
            float v = acc[r] + bias;
            short hi = f2bf(v);
            short lo = f2bf(v - bf2f(hi));
            qh[(size_t)(i0 + r) * KEYD + col] = hi;
            ql[(size_t)(i0 + r) * KEYD + col] = lo;
        }
    }
}

// ---------- Kernel B1: MFMA scores -> exp -> row sums only (NO P write) -------
// Same tiling as old score_kernel; epilogue just reduces. Scores recomputed
// bitwise-identically in B2, so normalization is consistent.
__global__ __launch_bounds__(256) void rowsum_kernel(
    const short* __restrict__ qh, const short* __restrict__ ql,
    const short* __restrict__ kh, const short* __restrict__ kl,
    float* __restrict__ rowsum)
{
    int t = threadIdx.x;
    int wave = t >> 6, l = t & 63;
    int quad = l >> 4, ln = l & 15;
    int i0 = blockIdx.y * 64;
    int j0 = blockIdx.x * 256 + wave * 64;

    short8_t ah[4][2], al[4][2];
#pragma unroll
    for (int r = 0; r < 4; r++)
#pragma unroll
        for (int ch = 0; ch < 2; ch++) {
            size_t off = (size_t)(i0 + r * 16 + ln) * KEYD + ch * 32 + quad * 8;
            ah[r][ch] = *(const short8_t*)(qh + off);
            al[r][ch] = *(const short8_t*)(ql + off);
        }

    float4_t acc[4][4];
#pragma unroll
    for (int r = 0; r < 4; r++)
#pragma unroll
        for (int c = 0; c < 4; c++) acc[r][c] = (float4_t)0.f;

#pragma unroll
    for (int c = 0; c < 4; c++) {
        int coln = j0 + c * 16 + ln;
#pragma unroll
        for (int ch = 0; ch < 2; ch++) {
            size_t off = (size_t)coln * KEYD + ch * 32 + quad * 8;
            short8_t bh = *(const short8_t*)(kh + off);
            short8_t bl = *(const short8_t*)(kl + off);
#pragma unroll
            for (int r = 0; r < 4; r++) {
                acc[r][c] = __builtin_amdgcn_mfma_f32_16x16x32_bf16(ah[r][ch], bh, acc[r][c], 0, 0, 0);
                acc[r][c] = __builtin_amdgcn_mfma_f32_16x16x32_bf16(ah[r][ch], bl, acc[r][c], 0, 0, 0);
                acc[r][c] = __builtin_amdgcn_mfma_f32_16x16x32_bf16(al[r][ch], bh, acc[r][c], 0, 0, 0);
            }
        }
    }

    float prow[4][4];
#pragma unroll
    for (int r = 0; r < 4; r++)
#pragma unroll
        for (int reg = 0; reg < 4; reg++) {
            int gi = i0 + r * 16 + quad * 4 + reg;
            float sum = 0.f;
#pragma unroll
            for (int c = 0; c < 4; c++) {
                float s = acc[r][c][reg] * 0.125f;
                s = fminf(fmaxf(s, -20.f), 20.f);
                int gj = j0 + c * 16 + ln;
                float p = (gi == gj) ? 0.f : __expf(s);
                sum += p;
            }
            prow[r][reg] = sum;
        }

#pragma unroll
    for (int off = 1; off < 16; off <<= 1)
#pragma unroll
        for (int r = 0; r < 4; r++)
#pragma unroll
            for (int reg = 0; reg < 4; reg++)
                prow[r][reg] += __shfl_xor(prow[r][reg], off);

    if (ln == 0) {
#pragma unroll
        for (int r = 0; r < 4; r++)
#pragma unroll
            for (int reg = 0; reg < 4; reg++)
                atomicAdd(&rowsum[i0 + r * 16 + quad * 4 + reg], prow[r][reg]);
    }
}

// ---- Kernel B2: recompute scores -> write NORMALIZED P once -> fused P@msg ---
// Block: 64 rows x (N/CSPLIT) cols; 4 waves, each wave owns 64 score cols per
// 256-col j-step and 16 attended rows. After the single barrier per j-step,
// the just-written fp32 P tile (64x256 = 64 KB, L2/L1-hot, same CU) is read
// back as the MFMA A-operand — no LDS transpose staging, no P round-trip.
__global__ __launch_bounds__(256) void attend_fused_kernel(
    const short* __restrict__ qh, const short* __restrict__ ql,
    const short* __restrict__ kh, const short* __restrict__ kl,
    const short* __restrict__ msgTb, const float* __restrict__ rowsum,
    float* __restrict__ P, float* __restrict__ att)
{
    __shared__ float inv_s[64];
    int t = threadIdx.x;
    int wave = t >> 6, l = t & 63;
    int quad = l >> 4, ln = l & 15;
    int i0 = blockIdx.y * 64;
    int cbase = blockIdx.x * (N_AGENTS / CSPLIT);

    if (t < 64) inv_s[t] = 1.0f / rowsum[i0 + t];

    // Q fragments: loaded once per block, reused across all j-steps
    short8_t ah[4][2], al[4][2];
#pragma unroll
    for (int r = 0; r < 4; r++)
#pragma unroll
        for (int ch = 0; ch < 2; ch++) {
            size_t off = (size_t)(i0 + r * 16 + ln) * KEYD + ch * 32 + quad * 8;
            ah[r][ch] = *(const short8_t*)(qh + off);
            al[r][ch] = *(const short8_t*)(ql + off);
        }

    __syncthreads();

    float vinv[4][4];
#pragma unroll
    for (int r = 0; r < 4; r++)
#pragma unroll
        for (int reg = 0; reg < 4; reg++)
            vinv[r][reg] = inv_s[r * 16 + quad * 4 + reg];

    float4_t accm[8];
#pragma unroll
    for (int c = 0; c < 8; c++) accm[c] = (float4_t)0.f;

    const int arow = i0 + wave * 16 + ln;

    for (int jt = cbase; jt < cbase + N_AGENTS / CSPLIT; jt += 256) {
        int j0 = jt + wave * 64;

        // ---- scores: identical MFMA sequence to rowsum_kernel ----
        float4_t acc[4][4];
#pragma unroll
        for (int r = 0; r < 4; r++)
#pragma unroll
            for (int c = 0; c < 4; c++) acc[r][c] = (float4_t)0.f;

#pragma unroll
        for (int c = 0; c < 4; c++) {
            int coln = j0 + c * 16 + ln;
#pragma unroll
            for (int ch = 0; ch < 2; ch++) {
                size_t off = (size_t)coln * KEYD + ch * 32 + quad * 8;
                short8_t bh = *(const short8_t*)(kh + off);
                short8_t bl = *(const short8_t*)(kl + off);
#pragma unroll
                for (int r = 0; r < 4; r++) {
                    acc[r][c] = __builtin_amdgcn_mfma_f32_16x16x32_bf16(ah[r][ch], bh, acc[r][c], 0, 0, 0);
                    acc[r][c] = __builtin_amdgcn_mfma_f32_16x16x32_bf16(ah[r][ch], bl, acc[r][c], 0, 0, 0);
                    acc[r][c] = __builtin_amdgcn_mfma_f32_16x16x32_bf16(al[r][ch], bh, acc[r][c], 0, 0, 0);
                }
            }
        }

        // ---- epilogue: normalize and write final P (single write) ----
#pragma unroll
        for (int r = 0; r < 4; r++)
#pragma unroll
            for (int reg = 0; reg < 4; reg++) {
                int gi = i0 + r * 16 + quad * 4 + reg;
                float iv = vinv[r][reg];
#pragma unroll
                for (int c = 0; c < 4; c++) {
                    float s = acc[r][c][reg] * 0.125f;
                    s = fminf(fmaxf(s, -20.f), 20.f);
                    int gj = j0 + c * 16 + ln;
                    float p = (gi == gj) ? 0.f : __expf(s) * iv;
                    P[(size_t)gi * N_AGENTS + gj] = p;
                }
            }

        // all 4 waves' P tile writes visible to this CU after the barrier
        __syncthreads();

        // ---- P @ msg: A-frags re-read from hot L2/L1, B from msgT (L2) ----
#pragma unroll
        for (int kc = 0; kc < 8; kc++) {
            const float* src = P + (size_t)arow * N_AGENTS + jt + kc * 32 + quad * 8;
            float4 f0 = *(const float4*)src;
            float4 f1 = *(const float4*)(src + 4);
            short8_t a;
            a[0] = f2bf(f0.x); a[1] = f2bf(f0.y); a[2] = f2bf(f0.z); a[3] = f2bf(f0.w);
            a[4] = f2bf(f1.x); a[5] = f2bf(f1.y); a[6] = f2bf(f1.z); a[7] = f2bf(f1.w);
#pragma unroll
            for (int c = 0; c < 8; c++) {
                short8_t b = *(const short8_t*)(msgTb + (size_t)(c * 16 + ln) * N_AGENTS + jt + kc * 32 + quad * 8);
                accm[c] = __builtin_amdgcn_mfma_f32_16x16x32_bf16(a, b, accm[c], 0, 0, 0);
            }
        }
        // no trailing barrier: next j-step writes a disjoint P region
    }

#pragma unroll
    for (int c = 0; c < 8; c++)
#pragma unroll
        for (int reg = 0; reg < 4; reg++) {
            int row = i0 + wave * 16 + quad * 4 + reg;
            int col = c * 16 + ln;
            atomicAdd(&att[(size_t)row * MSG + col], accm[c][reg]);
        }
}

// ---------------- Kernel D: GRU cell -----------------------------------------
__global__ __launch_bounds__(256) void gru_kernel(
    const float* __restrict__ att, const float* __restrict__ h,
    const float* __restrict__ Wir, const float* __restrict__ bir,
    const float* __restrict__ Wiz, const float* __restrict__ biz,
    const float* __restrict__ Win, const float* __restrict__ bin,
    const float* __restrict__ Whr, const float* __restrict__ Whz,
    const float* __restrict__ Whn, const float* __restrict__ bhn,
    float* __restrict__ hnew)
{
    const int R = 16;
    __shared__ float as_[R][MSG];
    __shared__ float hs[R][HIDDEN];
    int i0 = blockIdx.x * R;
    int t = threadIdx.x;  // 256
    int j = t;

    for (int l = t; l < R * MSG; l += 256) {
        int r = l >> 7, c = l & 127;
        as_[r][c] = att[(size_t)(i0 + r) * MSG + c];
    }
    for (int l = t; l < R * HIDDEN; l += 256) {
        int r = l >> 8, c = l & 255;
        hs[r][c] = h[(size_t)(i0 + r) * HIDDEN + c];
    }
    __syncthreads();

    float ar[R], az[R], an[R], hn[R];
#pragma unroll
    for (int r = 0; r < R; r++) { ar[r] = 0.f; az[r] = 0.f; an[r] = 0.f; hn[r] = 0.f; }

    for (int k = 0; k < MSG; k++) {
        float wr = Wir[(size_t)k * HIDDEN + j];
        float wz = Wiz[(size_t)k * HIDDEN + j];
        float wn = Win[(size_t)k * HIDDEN + j];
#pragma unroll
        for (int r = 0; r < R; r++) {
            float a = as_[r][k];
            ar[r] += a * wr; az[r] += a * wz; an[r] += a * wn;
        }
    }
    for (int k = 0; k < HIDDEN; k++) {
        float wr = Whr[(size_t)k * HIDDEN + j];
        float wz = Whz[(size_t)k * HIDDEN + j];
        float wn = Whn[(size_t)k * HIDDEN + j];
#pragma unroll
        for (int r = 0; r < R; r++) {
            float hv = hs[r][k];
            ar[r] += hv * wr; az[r] += hv * wz; hn[r] += hv * wn;
        }
    }

    float br = bir[j], bz = biz[j], bn = bin[j], bh = bhn[j];
#pragma unroll
    for (int r = 0; r < R; r++) {
        float rr = 1.f / (1.f + __expf(-(ar[r] + br)));
        float zz = 1.f / (1.f + __expf(-(az[r] + bz)));
        float cand = tanhf(an[r] + bn + rr * (hn[r] + bh));
        hnew[(size_t)(i0 + r) * HIDDEN + j] = (1.f - zz) * cand + zz * hs[r][j];
    }
}

// ---------------- launch ------------------------------------------------------
extern "C" void kernel_launch(void* const* d_in, const int* in_sizes, int n_in,
                              void* d_out, int out_size, void* d_ws, size_t ws_size,
                              hipStream_t stream)
{
    const float* h     = (const float*)d_in[0];
    const float* W_msg = (const float*)d_in[1];
    const float* b_msg = (const float*)d_in[2];
    const float* W_key = (const float*)d_in[3];
    const float* b_key = (const float*)d_in[4];
    const float* W_qry = (const float*)d_in[5];
    const float* b_qry = (const float*)d_in[6];
    const float* Wi_r  = (const float*)d_in[7];
    const float* bi_r  = (const float*)d_in[8];
    const float* Wi_z  = (const float*)d_in[9];
    const float* bi_z  = (const float*)d_in[10];
    const float* Wi_n  = (const float*)d_in[11];
    const float* bi_n  = (const float*)d_in[12];
    const float* Wh_r  = (const float*)d_in[13];
    const float* Wh_z  = (const float*)d_in[14];
    const float* Wh_n  = (const float*)d_in[15];
    const float* bh_n  = (const float*)d_in[16];

    float* out  = (float*)d_out;
    float* hnew = out;                                   // [8192,256]
    float* P    = out + (size_t)N_AGENTS * HIDDEN;       // attn region [8192,8192]

    float* ws     = (float*)d_ws;
    float* rowsum = ws;                                  // 8192 f32
    float* att    = ws + N_AGENTS;                       // 8192*128 f32
    short* sbase  = (short*)(att + (size_t)N_AGENTS * MSG);
    short* msgTb  = sbase;                                // 128*8192 bf16
    short* qh     = msgTb + (size_t)MSG * N_AGENTS;       // 8192*64
    short* ql     = qh + (size_t)N_AGENTS * KEYD;
    short* kh     = ql + (size_t)N_AGENTS * KEYD;
    short* kl     = kh + (size_t)N_AGENTS * KEYD;

    // zero rowsum + attended accumulator
    hipMemsetAsync(d_ws, 0, (size_t)(N_AGENTS + (size_t)N_AGENTS * MSG) * sizeof(float), stream);

    proj_kernel<<<N_AGENTS / 16, 256, 0, stream>>>(h, W_msg, b_msg, W_key, b_key,
                                                   W_qry, b_qry, msgTb, qh, ql, kh, kl);

    rowsum_kernel<<<dim3(N_AGENTS / 256, N_AGENTS / 64), 256, 0, stream>>>(qh, ql, kh, kl, rowsum);

    attend_fused_kernel<<<dim3(CSPLIT, N_AGENTS / 64), 256, 0, stream>>>(qh, ql, kh, kl,
                                                                         msgTb, rowsum, P, att);

    gru_kernel<<<N_AGENTS / 16, 256, 0, stream>>>(att, h, Wi_r, bi_r, Wi_z, bi_z,
                                                  Wi_n, bi_n, Wh_r, Wh_z, Wh_n, bh_n, hnew);
}

// Round 2
// 706.492 us; speedup vs baseline: 1.1849x; 1.1849x over previous
//
#include <hip/hip_runtime.h>
#include <math.h>

#define N_AGENTS 8192
#define HIDDEN   256
#define MSG      128
#define KEYD     64
#define CSPLIT   8

typedef __attribute__((ext_vector_type(8))) short short8_t;
typedef __attribute__((ext_vector_type(4))) short short4_t;
typedef __attribute__((ext_vector_type(4))) float float4_t;

__device__ __forceinline__ short f2bf(float x) {
    unsigned u = __float_as_uint(x);
    unsigned r = (u + 0x7fffu + ((u >> 16) & 1u)) >> 16;
    return (short)r;
}
__device__ __forceinline__ float bf2f(short b) {
    return __uint_as_float(((unsigned)(unsigned short)b) << 16);
}

// ---------------- Kernel A: projections -> bf16 side buffers ------------------
__global__ __launch_bounds__(256) void proj_kernel(
    const float* __restrict__ h,
    const float* __restrict__ Wm, const float* __restrict__ bm,
    const float* __restrict__ Wk, const float* __restrict__ bk,
    const float* __restrict__ Wq, const float* __restrict__ bq,
    short* __restrict__ msgTb,
    short* __restrict__ qh, short* __restrict__ ql,
    short* __restrict__ kh, short* __restrict__ kl)
{
    const int R = 16;
    __shared__ float hs[R][HIDDEN];
    int i0 = blockIdx.x * R;
    int t = threadIdx.x;  // 256

    for (int l = t; l < R * HIDDEN; l += 256) {
        int r = l >> 8, k = l & 255;
        hs[r][k] = h[(size_t)(i0 + r) * HIDDEN + k];
    }
    __syncthreads();

    int j = t;
    const float* Wp; int stride, col; float bias;
    if (j < 128)      { Wp = Wm; stride = 128; col = j;       bias = bm[col]; }
    else if (j < 192) { Wp = Wk; stride = 64;  col = j - 128; bias = bk[col]; }
    else              { Wp = Wq; stride = 64;  col = j - 192; bias = bq[col]; }

    float acc[R];
#pragma unroll
    for (int r = 0; r < R; r++) acc[r] = 0.f;

    for (int k = 0; k < HIDDEN; k++) {
        float w = Wp[(size_t)k * stride + col];
#pragma unroll
        for (int r = 0; r < R; r++) acc[r] += hs[r][k] * w;
    }

    if (j < 128) {
#pragma unroll
        for (int r = 0; r < R; r++)
            msgTb[(size_t)col * N_AGENTS + i0 + r] = f2bf(acc[r] + bias);
    } else if (j < 192) {
#pragma unroll
        for (int r = 0; r < R; r++) {
            float v = acc[r] + bias;
            short hi = f2bf(v);
            short lo = f2bf(v - bf2f(hi));
            kh[(size_t)(i0 + r) * KEYD + col] = hi;
            kl[(size_t)(i0 + r) * KEYD + col] = lo;
        }
    } else {
#pragma unroll
        for (int r = 0; r < R; r++) {
            float v = acc[r] + bias;
            short hi = f2bf(v);
            short lo = f2bf(v - bf2f(hi));
            qh[(size_t)(i0 + r) * KEYD + col] = hi;
            ql[(size_t)(i0 + r) * KEYD + col] = lo;
        }
    }
}

// ---------- Kernel B1: MFMA scores -> exp -> row sums only (NO P write) -------
// Scores recomputed bitwise-identically in B2, so normalization is consistent.
__global__ __launch_bounds__(256) void rowsum_kernel(
    const short* __restrict__ qh, const short* __restrict__ ql,
    const short* __restrict__ kh, const short* __restrict__ kl,
    float* __restrict__ rowsum)
{
    int t = threadIdx.x;
    int wave = t >> 6, l = t & 63;
    int quad = l >> 4, ln = l & 15;
    int i0 = blockIdx.y * 64;
    int j0 = blockIdx.x * 256 + wave * 64;

    short8_t ah[4][2], al[4][2];
#pragma unroll
    for (int r = 0; r < 4; r++)
#pragma unroll
        for (int ch = 0; ch < 2; ch++) {
            size_t off = (size_t)(i0 + r * 16 + ln) * KEYD + ch * 32 + quad * 8;
            ah[r][ch] = *(const short8_t*)(qh + off);
            al[r][ch] = *(const short8_t*)(ql + off);
        }

    float4_t acc[4][4];
#pragma unroll
    for (int r = 0; r < 4; r++)
#pragma unroll
        for (int c = 0; c < 4; c++) acc[r][c] = (float4_t)0.f;

#pragma unroll
    for (int c = 0; c < 4; c++) {
        int coln = j0 + c * 16 + ln;
#pragma unroll
        for (int ch = 0; ch < 2; ch++) {
            size_t off = (size_t)coln * KEYD + ch * 32 + quad * 8;
            short8_t bh = *(const short8_t*)(kh + off);
            short8_t bl = *(const short8_t*)(kl + off);
#pragma unroll
            for (int r = 0; r < 4; r++) {
                acc[r][c] = __builtin_amdgcn_mfma_f32_16x16x32_bf16(ah[r][ch], bh, acc[r][c], 0, 0, 0);
                acc[r][c] = __builtin_amdgcn_mfma_f32_16x16x32_bf16(ah[r][ch], bl, acc[r][c], 0, 0, 0);
                acc[r][c] = __builtin_amdgcn_mfma_f32_16x16x32_bf16(al[r][ch], bh, acc[r][c], 0, 0, 0);
            }
        }
    }

    float prow[4][4];
#pragma unroll
    for (int r = 0; r < 4; r++)
#pragma unroll
        for (int reg = 0; reg < 4; reg++) {
            int gi = i0 + r * 16 + quad * 4 + reg;
            float sum = 0.f;
#pragma unroll
            for (int c = 0; c < 4; c++) {
                float s = acc[r][c][reg] * 0.125f;
                s = fminf(fmaxf(s, -20.f), 20.f);
                int gj = j0 + c * 16 + ln;
                float p = (gi == gj) ? 0.f : __expf(s);
                sum += p;
            }
            prow[r][reg] = sum;
        }

#pragma unroll
    for (int off = 1; off < 16; off <<= 1)
#pragma unroll
        for (int r = 0; r < 4; r++)
#pragma unroll
            for (int reg = 0; reg < 4; reg++)
                prow[r][reg] += __shfl_xor(prow[r][reg], off);

    if (ln == 0) {
#pragma unroll
        for (int r = 0; r < 4; r++)
#pragma unroll
            for (int reg = 0; reg < 4; reg++)
                atomicAdd(&rowsum[i0 + r * 16 + quad * 4 + reg], prow[r][reg]);
    }
}

// ---- Kernel B2: recompute scores -> write NORMALIZED P once (nontemporal) ----
// P tile never round-trips: score epilogue stashes bf16(P) straight into LDS in
// the MFMA-A transpose layout; msgT is LDS-staged once per step (shared by all
// 4 waves, vs per-wave L2 reads that saturated L2 in the last version).
// Block: 64 rows x 1024 cols (CSPLIT=8), j-step 128; 4 waves.
//   scores: wave w owns cols [w*32, w*32+32) of the 128-col step (all 64 rows)
//   PV:     wave w owns att rows [w*16, w*16+16), all 128 msg cols
__global__ __launch_bounds__(256) void attend_fused_kernel(
    const short* __restrict__ qh, const short* __restrict__ ql,
    const short* __restrict__ kh, const short* __restrict__ kl,
    const short* __restrict__ msgTb, const float* __restrict__ rowsum,
    float* __restrict__ P, float* __restrict__ att)
{
    const int JB = 128;
    const int STR = JB + 8;            // 136 shorts: 272 B row stride, 16B-aligned
    __shared__ short A_lds[64][STR];   // normalized P tile, bf16
    __shared__ short B_lds[MSG][STR];  // msgT tile [col][k]
    __shared__ float inv_s[64];

    int t = threadIdx.x;
    int wave = t >> 6, l = t & 63;
    int quad = l >> 4, ln = l & 15;
    int i0 = blockIdx.y * 64;
    int kbase = blockIdx.x * (N_AGENTS / CSPLIT);

    if (t < 64) inv_s[t] = 1.0f / rowsum[i0 + t];

    // Q fragments: loaded once, reused across all 8 j-steps
    short8_t ah[4][2], al[4][2];
#pragma unroll
    for (int r = 0; r < 4; r++)
#pragma unroll
        for (int ch = 0; ch < 2; ch++) {
            size_t off = (size_t)(i0 + r * 16 + ln) * KEYD + ch * 32 + quad * 8;
            ah[r][ch] = *(const short8_t*)(qh + off);
            al[r][ch] = *(const short8_t*)(ql + off);
        }

    float4_t accm[8];
#pragma unroll
    for (int c = 0; c < 8; c++) accm[c] = (float4_t)0.f;

    __syncthreads();

    for (int jt = 0; jt < N_AGENTS / CSPLIT; jt += JB) {
        int kpos = kbase + jt;

        // ---- scores (registers only; same FP sequence as rowsum_kernel) ----
        float4_t acc[4][2];
#pragma unroll
        for (int r = 0; r < 4; r++)
#pragma unroll
            for (int c2 = 0; c2 < 2; c2++) acc[r][c2] = (float4_t)0.f;

#pragma unroll
        for (int c2 = 0; c2 < 2; c2++) {
            int coln = kpos + wave * 32 + c2 * 16 + ln;
#pragma unroll
            for (int ch = 0; ch < 2; ch++) {
                size_t off = (size_t)coln * KEYD + ch * 32 + quad * 8;
                short8_t bh = *(const short8_t*)(kh + off);
                short8_t bl = *(const short8_t*)(kl + off);
#pragma unroll
                for (int r = 0; r < 4; r++) {
                    acc[r][c2] = __builtin_amdgcn_mfma_f32_16x16x32_bf16(ah[r][ch], bh, acc[r][c2], 0, 0, 0);
                    acc[r][c2] = __builtin_amdgcn_mfma_f32_16x16x32_bf16(ah[r][ch], bl, acc[r][c2], 0, 0, 0);
                    acc[r][c2] = __builtin_amdgcn_mfma_f32_16x16x32_bf16(al[r][ch], bh, acc[r][c2], 0, 0, 0);
                }
            }
        }

        __syncthreads();   // previous step's PV reads of LDS complete

        // ---- stage msgT tile into regs (latency overlaps epilogue VALU) ----
        short8_t bst[8];
#pragma unroll
        for (int p = 0; p < 8; p++) {
            int idx = t + p * 256;         // 0..2047
            int c = idx >> 4, kk = (idx & 15) * 8;
            bst[p] = *(const short8_t*)(msgTb + (size_t)c * N_AGENTS + kpos + kk);
        }

        // ---- epilogue: normalize, write P once (nontemporal), stash to LDS ----
#pragma unroll
        for (int r = 0; r < 4; r++)
#pragma unroll
            for (int reg = 0; reg < 4; reg++) {
                int row = r * 16 + quad * 4 + reg;
                int gi = i0 + row;
                float iv = inv_s[row];
#pragma unroll
                for (int c2 = 0; c2 < 2; c2++) {
                    int col = wave * 32 + c2 * 16 + ln;
                    int gj = kpos + col;
                    float s = acc[r][c2][reg] * 0.125f;
                    s = fminf(fmaxf(s, -20.f), 20.f);
                    float p = (gi == gj) ? 0.f : __expf(s) * iv;
                    __builtin_nontemporal_store(p, &P[(size_t)gi * N_AGENTS + gj]);
                    A_lds[row][col] = f2bf(p);
                }
            }

        // ---- msgT regs -> LDS ----
#pragma unroll
        for (int p = 0; p < 8; p++) {
            int idx = t + p * 256;
            int c = idx >> 4, kk = (idx & 15) * 8;
            *(short8_t*)&B_lds[c][kk] = bst[p];
        }

        __syncthreads();   // A_lds + B_lds ready

        // ---- PV: accm += P_tile @ msgT_tile (k = 128 this step) ----
#pragma unroll
        for (int kc = 0; kc < 4; kc++) {
            short8_t a = *(short8_t*)&A_lds[wave * 16 + ln][kc * 32 + quad * 8];
#pragma unroll
            for (int c = 0; c < 8; c++) {
                short8_t b = *(short8_t*)&B_lds[c * 16 + ln][kc * 32 + quad * 8];
                accm[c] = __builtin_amdgcn_mfma_f32_16x16x32_bf16(a, b, accm[c], 0, 0, 0);
            }
        }
    }

#pragma unroll
    for (int c = 0; c < 8; c++)
#pragma unroll
        for (int reg = 0; reg < 4; reg++) {
            int row = i0 + wave * 16 + quad * 4 + reg;
            int col = c * 16 + ln;
            atomicAdd(&att[(size_t)row * MSG + col], accm[c][reg]);
        }
}

// ---------------- Kernel D: GRU cell -----------------------------------------
__global__ __launch_bounds__(256) void gru_kernel(
    const float* __restrict__ att, const float* __restrict__ h,
    const float* __restrict__ Wir, const float* __restrict__ bir,
    const float* __restrict__ Wiz, const float* __restrict__ biz,
    const float* __restrict__ Win, const float* __restrict__ bin,
    const float* __restrict__ Whr, const float* __restrict__ Whz,
    const float* __restrict__ Whn, const float* __restrict__ bhn,
    float* __restrict__ hnew)
{
    const int R = 16;
    __shared__ float as_[R][MSG];
    __shared__ float hs[R][HIDDEN];
    int i0 = blockIdx.x * R;
    int t = threadIdx.x;  // 256
    int j = t;

    for (int l = t; l < R * MSG; l += 256) {
        int r = l >> 7, c = l & 127;
        as_[r][c] = att[(size_t)(i0 + r) * MSG + c];
    }
    for (int l = t; l < R * HIDDEN; l += 256) {
        int r = l >> 8, c = l & 255;
        hs[r][c] = h[(size_t)(i0 + r) * HIDDEN + c];
    }
    __syncthreads();

    float ar[R], az[R], an[R], hn[R];
#pragma unroll
    for (int r = 0; r < R; r++) { ar[r] = 0.f; az[r] = 0.f; an[r] = 0.f; hn[r] = 0.f; }

    for (int k = 0; k < MSG; k++) {
        float wr = Wir[(size_t)k * HIDDEN + j];
        float wz = Wiz[(size_t)k * HIDDEN + j];
        float wn = Win[(size_t)k * HIDDEN + j];
#pragma unroll
        for (int r = 0; r < R; r++) {
            float a = as_[r][k];
            ar[r] += a * wr; az[r] += a * wz; an[r] += a * wn;
        }
    }
    for (int k = 0; k < HIDDEN; k++) {
        float wr = Whr[(size_t)k * HIDDEN + j];
        float wz = Whz[(size_t)k * HIDDEN + j];
        float wn = Whn[(size_t)k * HIDDEN + j];
#pragma unroll
        for (int r = 0; r < R; r++) {
            float hv = hs[r][k];
            ar[r] += hv * wr; az[r] += hv * wz; hn[r] += hv * wn;
        }
    }

    float br = bir[j], bz = biz[j], bn = bin[j], bh = bhn[j];
#pragma unroll
    for (int r = 0; r < R; r++) {
        float rr = 1.f / (1.f + __expf(-(ar[r] + br)));
        float zz = 1.f / (1.f + __expf(-(az[r] + bz)));
        float cand = tanhf(an[r] + bn + rr * (hn[r] + bh));
        hnew[(size_t)(i0 + r) * HIDDEN + j] = (1.f - zz) * cand + zz * hs[r][j];
    }
}

// ---------------- launch ------------------------------------------------------
extern "C" void kernel_launch(void* const* d_in, const int* in_sizes, int n_in,
                              void* d_out, int out_size, void* d_ws, size_t ws_size,
                              hipStream_t stream)
{
    const float* h     = (const float*)d_in[0];
    const float* W_msg = (const float*)d_in[1];
    const float* b_msg = (const float*)d_in[2];
    const float* W_key = (const float*)d_in[3];
    const float* b_key = (const float*)d_in[4];
    const float* W_qry = (const float*)d_in[5];
    const float* b_qry = (const float*)d_in[6];
    const float* Wi_r  = (const float*)d_in[7];
    const float* bi_r  = (const float*)d_in[8];
    const float* Wi_z  = (const float*)d_in[9];
    const float* bi_z  = (const float*)d_in[10];
    const float* Wi_n  = (const float*)d_in[11];
    const float* bi_n  = (const float*)d_in[12];
    const float* Wh_r  = (const float*)d_in[13];
    const float* Wh_z  = (const float*)d_in[14];
    const float* Wh_n  = (const float*)d_in[15];
    const float* bh_n  = (const float*)d_in[16];

    float* out  = (float*)d_out;
    float* hnew = out;                                   // [8192,256]
    float* P    = out + (size_t)N_AGENTS * HIDDEN;       // attn region [8192,8192]

    float* ws     = (float*)d_ws;
    float* rowsum = ws;                                  // 8192 f32
    float* att    = ws + N_AGENTS;                       // 8192*128 f32
    short* sbase  = (short*)(att + (size_t)N_AGENTS * MSG);
    short* msgTb  = sbase;                                // 128*8192 bf16
    short* qh     = msgTb + (size_t)MSG * N_AGENTS;       // 8192*64
    short* ql     = qh + (size_t)N_AGENTS * KEYD;
    short* kh     = ql + (size_t)N_AGENTS * KEYD;
    short* kl     = kh + (size_t)N_AGENTS * KEYD;

    // zero rowsum + attended accumulator
    hipMemsetAsync(d_ws, 0, (size_t)(N_AGENTS + (size_t)N_AGENTS * MSG) * sizeof(float), stream);

    proj_kernel<<<N_AGENTS / 16, 256, 0, stream>>>(h, W_msg, b_msg, W_key, b_key,
                                                   W_qry, b_qry, msgTb, qh, ql, kh, kl);

    rowsum_kernel<<<dim3(N_AGENTS / 256, N_AGENTS / 64), 256, 0, stream>>>(qh, ql, kh, kl, rowsum);

    attend_fused_kernel<<<dim3(CSPLIT, N_AGENTS / 64), 256, 0, stream>>>(qh, ql, kh, kl,
                                                                         msgTb, rowsum, P, att);

    gru_kernel<<<N_AGENTS / 16, 256, 0, stream>>>(att, h, Wi_r, bi_r, Wi_z, bi_z,
                                                  Wi_n, bi_n, Wh_r, Wh_z, Wh_n, bh_n, hnew);
}

// Round 3
// 609.895 us; speedup vs baseline: 1.3725x; 1.1584x over previous
//
#include <hip/hip_runtime.h>
#include <math.h>

#define N_AGENTS 8192
#define HIDDEN   256
#define MSG      128
#define KEYD     64
#define CSPLIT   8

// ---- transposed hi/lo bf16 weight cache layout (shorts, in workspace) -------
#define OFF_WM_H   0        // [128][256]
#define OFF_WM_L   32768
#define OFF_WK_H   65536    // [64][256]
#define OFF_WK_L   81920
#define OFF_WQ_H   98304
#define OFF_WQ_L   114688
#define OFF_WIR_H  131072   // [256][128]
#define OFF_WIR_L  163840
#define OFF_WIZ_H  196608
#define OFF_WIZ_L  229376
#define OFF_WIN_H  262144
#define OFF_WIN_L  294912
#define OFF_WHR_H  327680   // [256][256]
#define OFF_WHR_L  393216
#define OFF_WHZ_H  458752
#define OFF_WHZ_L  524288
#define OFF_WHN_H  589824
#define OFF_WHN_L  655360
#define WT_TOTAL   720896

typedef __attribute__((ext_vector_type(8))) short short8_t;
typedef __attribute__((ext_vector_type(4))) short short4_t;
typedef __attribute__((ext_vector_type(4))) float float4_t;

__device__ __forceinline__ short f2bf(float x) {
    unsigned u = __float_as_uint(x);
    unsigned r = (u + 0x7fffu + ((u >> 16) & 1u)) >> 16;
    return (short)r;
}
__device__ __forceinline__ float bf2f(short b) {
    return __uint_as_float(((unsigned)(unsigned short)b) << 16);
}
__device__ __forceinline__ void split4(float4 v, short4_t* hi, short4_t* lo) {
    (*hi)[0] = f2bf(v.x); (*lo)[0] = f2bf(v.x - bf2f((*hi)[0]));
    (*hi)[1] = f2bf(v.y); (*lo)[1] = f2bf(v.y - bf2f((*hi)[1]));
    (*hi)[2] = f2bf(v.z); (*lo)[2] = f2bf(v.z - bf2f((*hi)[2]));
    (*hi)[3] = f2bf(v.w); (*lo)[3] = f2bf(v.w - bf2f((*hi)[3]));
}

// ---------- Kernel P0: weights -> transposed hi/lo bf16 (runs once) -----------
__global__ __launch_bounds__(256) void prep_weights(
    const float* __restrict__ Wm, const float* __restrict__ Wk, const float* __restrict__ Wq,
    const float* __restrict__ Wir, const float* __restrict__ Wiz, const float* __restrict__ Win,
    const float* __restrict__ Whr, const float* __restrict__ Whz, const float* __restrict__ Whn,
    short* __restrict__ wT)
{
    int idx = blockIdx.x * 256 + threadIdx.x;   // 0..360447
    const float* src; int K, lgC, local; size_t oh, ol;
    if (idx < 32768)        { src = Wm;  K = 256; lgC = 7; local = idx;          oh = OFF_WM_H;  ol = OFF_WM_L; }
    else if (idx < 49152)   { src = Wk;  K = 256; lgC = 6; local = idx - 32768;  oh = OFF_WK_H;  ol = OFF_WK_L; }
    else if (idx < 65536)   { src = Wq;  K = 256; lgC = 6; local = idx - 49152;  oh = OFF_WQ_H;  ol = OFF_WQ_L; }
    else if (idx < 98304)   { src = Wir; K = 128; lgC = 8; local = idx - 65536;  oh = OFF_WIR_H; ol = OFF_WIR_L; }
    else if (idx < 131072)  { src = Wiz; K = 128; lgC = 8; local = idx - 98304;  oh = OFF_WIZ_H; ol = OFF_WIZ_L; }
    else if (idx < 163840)  { src = Win; K = 128; lgC = 8; local = idx - 131072; oh = OFF_WIN_H; ol = OFF_WIN_L; }
    else if (idx < 229376)  { src = Whr; K = 256; lgC = 8; local = idx - 163840; oh = OFF_WHR_H; ol = OFF_WHR_L; }
    else if (idx < 294912)  { src = Whz; K = 256; lgC = 8; local = idx - 229376; oh = OFF_WHZ_H; ol = OFF_WHZ_L; }
    else if (idx < 360448)  { src = Whn; K = 256; lgC = 8; local = idx - 294912; oh = OFF_WHN_H; ol = OFF_WHN_L; }
    else return;
    int k = local >> lgC, c = local & ((1 << lgC) - 1);   // src row-major [k][c]
    float v = src[local];
    short hi = f2bf(v);
    short lo = f2bf(v - bf2f(hi));
    wT[oh + (size_t)c * K + k] = hi;
    wT[ol + (size_t)c * K + k] = lo;
}

// ---------------- Kernel A: projections via MFMA (hi/lo x hi/lo) --------------
// 512 blocks x 16 rows; 4 waves: waves 0,1 -> msg cols, wave 2 -> key, wave 3 -> qry
__global__ __launch_bounds__(256) void proj_mfma_kernel(
    const float* __restrict__ h, const short* __restrict__ wT,
    const float* __restrict__ bm, const float* __restrict__ bk, const float* __restrict__ bq,
    short* __restrict__ msgTb,
    short* __restrict__ qh, short* __restrict__ ql,
    short* __restrict__ kh, short* __restrict__ kl)
{
    __shared__ short hh[16][264], hl[16][264];   // +8 pad: 2-way max on frag reads
    int t = threadIdx.x;
    int wave = t >> 6, l = t & 63, quad = l >> 4, ln = l & 15;
    int i0 = blockIdx.x * 16;

    // stage h rows -> hi/lo LDS (16 x 256 f32)
#pragma unroll
    for (int p = 0; p < 4; p++) {
        int idx = t + p * 256;           // 0..1023 float4s
        int r = idx >> 6, k4 = (idx & 63) * 4;
        float4 v = *(const float4*)&h[(size_t)(i0 + r) * HIDDEN + k4];
        short4_t hv, lv;
        split4(v, &hv, &lv);
        *(short4_t*)&hh[r][k4] = hv;
        *(short4_t*)&hl[r][k4] = lv;
    }
    __syncthreads();

    size_t base_h, base_l; int cb;
    if (wave < 2)      { base_h = OFF_WM_H; base_l = OFF_WM_L; cb = wave * 64; }
    else if (wave == 2){ base_h = OFF_WK_H; base_l = OFF_WK_L; cb = 0; }
    else               { base_h = OFF_WQ_H; base_l = OFF_WQ_L; cb = 0; }

    float4_t acc[4];
#pragma unroll
    for (int nt = 0; nt < 4; nt++) acc[nt] = (float4_t)0.f;

    for (int ch = 0; ch < 8; ch++) {
        short8_t a_h = *(short8_t*)&hh[ln][ch * 32 + quad * 8];
        short8_t a_l = *(short8_t*)&hl[ln][ch * 32 + quad * 8];
#pragma unroll
        for (int nt = 0; nt < 4; nt++) {
            int c = cb + nt * 16 + ln;
            const short* bp_h = wT + base_h + (size_t)c * 256 + ch * 32 + quad * 8;
            const short* bp_l = wT + base_l + (size_t)c * 256 + ch * 32 + quad * 8;
            short8_t b_h = *(const short8_t*)bp_h;
            short8_t b_l = *(const short8_t*)bp_l;
            acc[nt] = __builtin_amdgcn_mfma_f32_16x16x32_bf16(a_h, b_h, acc[nt], 0, 0, 0);
            acc[nt] = __builtin_amdgcn_mfma_f32_16x16x32_bf16(a_h, b_l, acc[nt], 0, 0, 0);
            acc[nt] = __builtin_amdgcn_mfma_f32_16x16x32_bf16(a_l, b_h, acc[nt], 0, 0, 0);
        }
    }

    if (wave < 2) {
#pragma unroll
        for (int nt = 0; nt < 4; nt++) {
            int col = cb + nt * 16 + ln;
            float b = bm[col];
            short4_t o;
#pragma unroll
            for (int reg = 0; reg < 4; reg++) o[reg] = f2bf(acc[nt][reg] + b);
            *(short4_t*)&msgTb[(size_t)col * N_AGENTS + i0 + quad * 4] = o;
        }
    } else {
        short* dh = (wave == 2) ? kh : qh;
        short* dl = (wave == 2) ? kl : ql;
        const float* bias = (wave == 2) ? bk : bq;
#pragma unroll
        for (int nt = 0; nt < 4; nt++) {
            int col = nt * 16 + ln;
            float b = bias[col];
#pragma unroll
            for (int reg = 0; reg < 4; reg++) {
                int row = i0 + quad * 4 + reg;
                float v = acc[nt][reg] + b;
                short hi = f2bf(v);
                short lo = f2bf(v - bf2f(hi));
                dh[(size_t)row * KEYD + col] = hi;
                dl[(size_t)row * KEYD + col] = lo;
            }
        }
    }
}

// ---------- Kernel B1: MFMA scores -> exp -> row sums only (NO P write) -------
// Scores recomputed bitwise-identically in B2, so normalization is consistent.
__global__ __launch_bounds__(256) void rowsum_kernel(
    const short* __restrict__ qh, const short* __restrict__ ql,
    const short* __restrict__ kh, const short* __restrict__ kl,
    float* __restrict__ rowsum)
{
    int t = threadIdx.x;
    int wave = t >> 6, l = t & 63;
    int quad = l >> 4, ln = l & 15;
    int i0 = blockIdx.y * 64;
    int j0 = blockIdx.x * 256 + wave * 64;

    short8_t ah[4][2], al[4][2];
#pragma unroll
    for (int r = 0; r < 4; r++)
#pragma unroll
        for (int ch = 0; ch < 2; ch++) {
            size_t off = (size_t)(i0 + r * 16 + ln) * KEYD + ch * 32 + quad * 8;
            ah[r][ch] = *(const short8_t*)(qh + off);
            al[r][ch] = *(const short8_t*)(ql + off);
        }

    float4_t acc[4][4];
#pragma unroll
    for (int r = 0; r < 4; r++)
#pragma unroll
        for (int c = 0; c < 4; c++) acc[r][c] = (float4_t)0.f;

#pragma unroll
    for (int c = 0; c < 4; c++) {
        int coln = j0 + c * 16 + ln;
#pragma unroll
        for (int ch = 0; ch < 2; ch++) {
            size_t off = (size_t)coln * KEYD + ch * 32 + quad * 8;
            short8_t bh = *(const short8_t*)(kh + off);
            short8_t bl = *(const short8_t*)(kl + off);
#pragma unroll
            for (int r = 0; r < 4; r++) {
                acc[r][c] = __builtin_amdgcn_mfma_f32_16x16x32_bf16(ah[r][ch], bh, acc[r][c], 0, 0, 0);
                acc[r][c] = __builtin_amdgcn_mfma_f32_16x16x32_bf16(ah[r][ch], bl, acc[r][c], 0, 0, 0);
                acc[r][c] = __builtin_amdgcn_mfma_f32_16x16x32_bf16(al[r][ch], bh, acc[r][c], 0, 0, 0);
            }
        }
    }

    float prow[4][4];
#pragma unroll
    for (int r = 0; r < 4; r++)
#pragma unroll
        for (int reg = 0; reg < 4; reg++) {
            int gi = i0 + r * 16 + quad * 4 + reg;
            float sum = 0.f;
#pragma unroll
            for (int c = 0; c < 4; c++) {
                float s = acc[r][c][reg] * 0.125f;
                s = fminf(fmaxf(s, -20.f), 20.f);
                int gj = j0 + c * 16 + ln;
                float p = (gi == gj) ? 0.f : __expf(s);
                sum += p;
            }
            prow[r][reg] = sum;
        }

#pragma unroll
    for (int off = 1; off < 16; off <<= 1)
#pragma unroll
        for (int r = 0; r < 4; r++)
#pragma unroll
            for (int reg = 0; reg < 4; reg++)
                prow[r][reg] += __shfl_xor(prow[r][reg], off);

    if (ln == 0) {
#pragma unroll
        for (int r = 0; r < 4; r++)
#pragma unroll
            for (int reg = 0; reg < 4; reg++)
                atomicAdd(&rowsum[i0 + r * 16 + quad * 4 + reg], prow[r][reg]);
    }
}

// ---- Kernel B2: recompute scores -> write NORMALIZED P once (nontemporal) ----
__global__ __launch_bounds__(256) void attend_fused_kernel(
    const short* __restrict__ qh, const short* __restrict__ ql,
    const short* __restrict__ kh, const short* __restrict__ kl,
    const short* __restrict__ msgTb, const float* __restrict__ rowsum,
    float* __restrict__ P, float* __restrict__ att)
{
    const int JB = 128;
    const int STR = JB + 8;            // 136 shorts: 272 B row stride, 16B-aligned
    __shared__ short A_lds[64][STR];   // normalized P tile, bf16
    __shared__ short B_lds[MSG][STR];  // msgT tile [col][k]
    __shared__ float inv_s[64];

    int t = threadIdx.x;
    int wave = t >> 6, l = t & 63;
    int quad = l >> 4, ln = l & 15;
    int i0 = blockIdx.y * 64;
    int kbase = blockIdx.x * (N_AGENTS / CSPLIT);

    if (t < 64) inv_s[t] = 1.0f / rowsum[i0 + t];

    short8_t ah[4][2], al[4][2];
#pragma unroll
    for (int r = 0; r < 4; r++)
#pragma unroll
        for (int ch = 0; ch < 2; ch++) {
            size_t off = (size_t)(i0 + r * 16 + ln) * KEYD + ch * 32 + quad * 8;
            ah[r][ch] = *(const short8_t*)(qh + off);
            al[r][ch] = *(const short8_t*)(ql + off);
        }

    float4_t accm[8];
#pragma unroll
    for (int c = 0; c < 8; c++) accm[c] = (float4_t)0.f;

    __syncthreads();

    for (int jt = 0; jt < N_AGENTS / CSPLIT; jt += JB) {
        int kpos = kbase + jt;

        // ---- scores (registers only; same FP sequence as rowsum_kernel) ----
        float4_t acc[4][2];
#pragma unroll
        for (int r = 0; r < 4; r++)
#pragma unroll
            for (int c2 = 0; c2 < 2; c2++) acc[r][c2] = (float4_t)0.f;

#pragma unroll
        for (int c2 = 0; c2 < 2; c2++) {
            int coln = kpos + wave * 32 + c2 * 16 + ln;
#pragma unroll
            for (int ch = 0; ch < 2; ch++) {
                size_t off = (size_t)coln * KEYD + ch * 32 + quad * 8;
                short8_t bh = *(const short8_t*)(kh + off);
                short8_t bl = *(const short8_t*)(kl + off);
#pragma unroll
                for (int r = 0; r < 4; r++) {
                    acc[r][c2] = __builtin_amdgcn_mfma_f32_16x16x32_bf16(ah[r][ch], bh, acc[r][c2], 0, 0, 0);
                    acc[r][c2] = __builtin_amdgcn_mfma_f32_16x16x32_bf16(ah[r][ch], bl, acc[r][c2], 0, 0, 0);
                    acc[r][c2] = __builtin_amdgcn_mfma_f32_16x16x32_bf16(al[r][ch], bh, acc[r][c2], 0, 0, 0);
                }
            }
        }

        __syncthreads();   // previous step's PV reads of LDS complete

        // ---- stage msgT tile into regs (latency overlaps epilogue VALU) ----
        short8_t bst[8];
#pragma unroll
        for (int p = 0; p < 8; p++) {
            int idx = t + p * 256;         // 0..2047
            int c = idx >> 4, kk = (idx & 15) * 8;
            bst[p] = *(const short8_t*)(msgTb + (size_t)c * N_AGENTS + kpos + kk);
        }

        // ---- epilogue: normalize, write P once (nontemporal), stash to LDS ----
#pragma unroll
        for (int r = 0; r < 4; r++)
#pragma unroll
            for (int reg = 0; reg < 4; reg++) {
                int row = r * 16 + quad * 4 + reg;
                int gi = i0 + row;
                float iv = inv_s[row];
#pragma unroll
                for (int c2 = 0; c2 < 2; c2++) {
                    int col = wave * 32 + c2 * 16 + ln;
                    int gj = kpos + col;
                    float s = acc[r][c2][reg] * 0.125f;
                    s = fminf(fmaxf(s, -20.f), 20.f);
                    float p = (gi == gj) ? 0.f : __expf(s) * iv;
                    __builtin_nontemporal_store(p, &P[(size_t)gi * N_AGENTS + gj]);
                    A_lds[row][col] = f2bf(p);
                }
            }

        // ---- msgT regs -> LDS ----
#pragma unroll
        for (int p = 0; p < 8; p++) {
            int idx = t + p * 256;
            int c = idx >> 4, kk = (idx & 15) * 8;
            *(short8_t*)&B_lds[c][kk] = bst[p];
        }

        __syncthreads();   // A_lds + B_lds ready

        // ---- PV: accm += P_tile @ msgT_tile (k = 128 this step) ----
#pragma unroll
        for (int kc = 0; kc < 4; kc++) {
            short8_t a = *(short8_t*)&A_lds[wave * 16 + ln][kc * 32 + quad * 8];
#pragma unroll
            for (int c = 0; c < 8; c++) {
                short8_t b = *(short8_t*)&B_lds[c * 16 + ln][kc * 32 + quad * 8];
                accm[c] = __builtin_amdgcn_mfma_f32_16x16x32_bf16(a, b, accm[c], 0, 0, 0);
            }
        }
    }

#pragma unroll
    for (int c = 0; c < 8; c++)
#pragma unroll
        for (int reg = 0; reg < 4; reg++) {
            int row = i0 + wave * 16 + quad * 4 + reg;
            int col = c * 16 + ln;
            atomicAdd(&att[(size_t)row * MSG + col], accm[c][reg]);
        }
}

// ---------------- Kernel D: GRU cell via MFMA (hi/lo x hi/lo) -----------------
// 512 blocks x 16 rows; 4 waves x 64 cols. Separate accs: ar,az (att+h), an (att), hn (h)
__global__ __launch_bounds__(256) void gru_mfma_kernel(
    const float* __restrict__ att, const float* __restrict__ h,
    const short* __restrict__ wT,
    const float* __restrict__ bir, const float* __restrict__ biz,
    const float* __restrict__ bin, const float* __restrict__ bhn,
    float* __restrict__ hnew)
{
    __shared__ short ath[16][136], atl[16][136];  // att hi/lo
    __shared__ short hh[16][264], hl[16][264];    // h hi/lo
    int t = threadIdx.x;
    int wave = t >> 6, l = t & 63, quad = l >> 4, ln = l & 15;
    int i0 = blockIdx.x * 16;
    int cb = wave * 64;

    // stage att (16 x 128 f32)
#pragma unroll
    for (int p = 0; p < 2; p++) {
        int idx = t + p * 256;           // 0..511 float4s
        int r = idx >> 5, c4 = (idx & 31) * 4;
        float4 v = *(const float4*)&att[(size_t)(i0 + r) * MSG + c4];
        short4_t hv, lv;
        split4(v, &hv, &lv);
        *(short4_t*)&ath[r][c4] = hv;
        *(short4_t*)&atl[r][c4] = lv;
    }
    // stage h (16 x 256 f32)
#pragma unroll
    for (int p = 0; p < 4; p++) {
        int idx = t + p * 256;           // 0..1023 float4s
        int r = idx >> 6, k4 = (idx & 63) * 4;
        float4 v = *(const float4*)&h[(size_t)(i0 + r) * HIDDEN + k4];
        short4_t hv, lv;
        split4(v, &hv, &lv);
        *(short4_t*)&hh[r][k4] = hv;
        *(short4_t*)&hl[r][k4] = lv;
    }
    __syncthreads();

    float4_t ar[4], az[4], an[4], hn[4];
#pragma unroll
    for (int nt = 0; nt < 4; nt++) {
        ar[nt] = (float4_t)0.f; az[nt] = (float4_t)0.f;
        an[nt] = (float4_t)0.f; hn[nt] = (float4_t)0.f;
    }

#define MFMA3(ACC, AH, AL, BH, BL)                                              \
    ACC = __builtin_amdgcn_mfma_f32_16x16x32_bf16(AH, BH, ACC, 0, 0, 0);        \
    ACC = __builtin_amdgcn_mfma_f32_16x16x32_bf16(AH, BL, ACC, 0, 0, 0);        \
    ACC = __builtin_amdgcn_mfma_f32_16x16x32_bf16(AL, BH, ACC, 0, 0, 0);

    // att @ Wi_{r,z,n} : K = 128, 4 chunks
    for (int ch = 0; ch < 4; ch++) {
        short8_t a_h = *(short8_t*)&ath[ln][ch * 32 + quad * 8];
        short8_t a_l = *(short8_t*)&atl[ln][ch * 32 + quad * 8];
#pragma unroll
        for (int nt = 0; nt < 4; nt++) {
            size_t cw = (size_t)(cb + nt * 16 + ln) * 128 + ch * 32 + quad * 8;
            short8_t brh = *(const short8_t*)(wT + OFF_WIR_H + cw);
            short8_t brl = *(const short8_t*)(wT + OFF_WIR_L + cw);
            MFMA3(ar[nt], a_h, a_l, brh, brl);
            short8_t bzh = *(const short8_t*)(wT + OFF_WIZ_H + cw);
            short8_t bzl = *(const short8_t*)(wT + OFF_WIZ_L + cw);
            MFMA3(az[nt], a_h, a_l, bzh, bzl);
            short8_t bnh = *(const short8_t*)(wT + OFF_WIN_H + cw);
            short8_t bnl = *(const short8_t*)(wT + OFF_WIN_L + cw);
            MFMA3(an[nt], a_h, a_l, bnh, bnl);
        }
    }

    // h @ Wh_{r,z,n} : K = 256, 8 chunks
    for (int ch = 0; ch < 8; ch++) {
        short8_t a_h = *(short8_t*)&hh[ln][ch * 32 + quad * 8];
        short8_t a_l = *(short8_t*)&hl[ln][ch * 32 + quad * 8];
#pragma unroll
        for (int nt = 0; nt < 4; nt++) {
            size_t cw = (size_t)(cb + nt * 16 + ln) * 256 + ch * 32 + quad * 8;
            short8_t brh = *(const short8_t*)(wT + OFF_WHR_H + cw);
            short8_t brl = *(const short8_t*)(wT + OFF_WHR_L + cw);
            MFMA3(ar[nt], a_h, a_l, brh, brl);
            short8_t bzh = *(const short8_t*)(wT + OFF_WHZ_H + cw);
            short8_t bzl = *(const short8_t*)(wT + OFF_WHZ_L + cw);
            MFMA3(az[nt], a_h, a_l, bzh, bzl);
            short8_t bnh = *(const short8_t*)(wT + OFF_WHN_H + cw);
            short8_t bnl = *(const short8_t*)(wT + OFF_WHN_L + cw);
            MFMA3(hn[nt], a_h, a_l, bnh, bnl);
        }
    }
#undef MFMA3

    // epilogue: gates + blend (fp32)
#pragma unroll
    for (int nt = 0; nt < 4; nt++) {
        int col = cb + nt * 16 + ln;
        float br = bir[col], bz = biz[col], bn = bin[col], bh_ = bhn[col];
#pragma unroll
        for (int reg = 0; reg < 4; reg++) {
            int row = i0 + quad * 4 + reg;
            float hv = h[(size_t)row * HIDDEN + col];
            float rr = 1.f / (1.f + __expf(-(ar[nt][reg] + br)));
            float zz = 1.f / (1.f + __expf(-(az[nt][reg] + bz)));
            float cand = tanhf(an[nt][reg] + bn + rr * (hn[nt][reg] + bh_));
            hnew[(size_t)row * HIDDEN + col] = (1.f - zz) * cand + zz * hv;
        }
    }
}

// ---------------- launch ------------------------------------------------------
extern "C" void kernel_launch(void* const* d_in, const int* in_sizes, int n_in,
                              void* d_out, int out_size, void* d_ws, size_t ws_size,
                              hipStream_t stream)
{
    const float* h     = (const float*)d_in[0];
    const float* W_msg = (const float*)d_in[1];
    const float* b_msg = (const float*)d_in[2];
    const float* W_key = (const float*)d_in[3];
    const float* b_key = (const float*)d_in[4];
    const float* W_qry = (const float*)d_in[5];
    const float* b_qry = (const float*)d_in[6];
    const float* Wi_r  = (const float*)d_in[7];
    const float* bi_r  = (const float*)d_in[8];
    const float* Wi_z  = (const float*)d_in[9];
    const float* bi_z  = (const float*)d_in[10];
    const float* Wi_n  = (const float*)d_in[11];
    const float* bi_n  = (const float*)d_in[12];
    const float* Wh_r  = (const float*)d_in[13];
    const float* Wh_z  = (const float*)d_in[14];
    const float* Wh_n  = (const float*)d_in[15];
    const float* bh_n  = (const float*)d_in[16];

    float* out  = (float*)d_out;
    float* hnew = out;                                   // [8192,256]
    float* P    = out + (size_t)N_AGENTS * HIDDEN;       // attn region [8192,8192]

    float* ws     = (float*)d_ws;
    float* rowsum = ws;                                  // 8192 f32
    float* att    = ws + N_AGENTS;                       // 8192*128 f32
    short* sbase  = (short*)(att + (size_t)N_AGENTS * MSG);
    short* msgTb  = sbase;                                // 128*8192 bf16
    short* qh     = msgTb + (size_t)MSG * N_AGENTS;       // 8192*64
    short* ql     = qh + (size_t)N_AGENTS * KEYD;
    short* kh     = ql + (size_t)N_AGENTS * KEYD;
    short* kl     = kh + (size_t)N_AGENTS * KEYD;
    short* wT     = kl + (size_t)N_AGENTS * KEYD;         // 720896 shorts

    // zero rowsum + attended accumulator
    hipMemsetAsync(d_ws, 0, (size_t)(N_AGENTS + (size_t)N_AGENTS * MSG) * sizeof(float), stream);

    prep_weights<<<1408, 256, 0, stream>>>(W_msg, W_key, W_qry, Wi_r, Wi_z, Wi_n,
                                           Wh_r, Wh_z, Wh_n, wT);

    proj_mfma_kernel<<<N_AGENTS / 16, 256, 0, stream>>>(h, wT, b_msg, b_key, b_qry,
                                                        msgTb, qh, ql, kh, kl);

    rowsum_kernel<<<dim3(N_AGENTS / 256, N_AGENTS / 64), 256, 0, stream>>>(qh, ql, kh, kl, rowsum);

    attend_fused_kernel<<<dim3(CSPLIT, N_AGENTS / 64), 256, 0, stream>>>(qh, ql, kh, kl,
                                                                         msgTb, rowsum, P, att);

    gru_mfma_kernel<<<N_AGENTS / 16, 256, 0, stream>>>(att, h, wT, bi_r, bi_z, bi_n, bh_n, hnew);
}

// Round 4
// 595.839 us; speedup vs baseline: 1.4049x; 1.0236x over previous
//
#include <hip/hip_runtime.h>
#include <math.h>

#define N_AGENTS 8192
#define HIDDEN   256
#define MSG      128
#define KEYD     64
#define CSPLIT   4

// ---- transposed hi/lo bf16 weight cache layout (shorts, in workspace) -------
#define OFF_WM_H   0        // [128][256]
#define OFF_WM_L   32768
#define OFF_WK_H   65536    // [64][256]
#define OFF_WK_L   81920
#define OFF_WQ_H   98304
#define OFF_WQ_L   114688
#define OFF_WIR_H  131072   // [256][128]
#define OFF_WIR_L  163840
#define OFF_WIZ_H  196608
#define OFF_WIZ_L  229376
#define OFF_WIN_H  262144
#define OFF_WIN_L  294912
#define OFF_WHR_H  327680   // [256][256]
#define OFF_WHR_L  393216
#define OFF_WHZ_H  458752
#define OFF_WHZ_L  524288
#define OFF_WHN_H  589824
#define OFF_WHN_L  655360
#define WT_TOTAL   720896

typedef __attribute__((ext_vector_type(8))) short short8_t;
typedef __attribute__((ext_vector_type(4))) short short4_t;
typedef __attribute__((ext_vector_type(4))) float float4_t;

__device__ __forceinline__ short f2bf(float x) {
    unsigned u = __float_as_uint(x);
    unsigned r = (u + 0x7fffu + ((u >> 16) & 1u)) >> 16;
    return (short)r;
}
__device__ __forceinline__ float bf2f(short b) {
    return __uint_as_float(((unsigned)(unsigned short)b) << 16);
}
__device__ __forceinline__ void split4(float4 v, short4_t* hi, short4_t* lo) {
    (*hi)[0] = f2bf(v.x); (*lo)[0] = f2bf(v.x - bf2f((*hi)[0]));
    (*hi)[1] = f2bf(v.y); (*lo)[1] = f2bf(v.y - bf2f((*hi)[1]));
    (*hi)[2] = f2bf(v.z); (*lo)[2] = f2bf(v.z - bf2f((*hi)[2]));
    (*hi)[3] = f2bf(v.w); (*lo)[3] = f2bf(v.w - bf2f((*hi)[3]));
}

// ---------- Kernel P0: weights -> transposed hi/lo bf16 (runs once) -----------
__global__ __launch_bounds__(256) void prep_weights(
    const float* __restrict__ Wm, const float* __restrict__ Wk, const float* __restrict__ Wq,
    const float* __restrict__ Wir, const float* __restrict__ Wiz, const float* __restrict__ Win,
    const float* __restrict__ Whr, const float* __restrict__ Whz, const float* __restrict__ Whn,
    short* __restrict__ wT)
{
    int idx = blockIdx.x * 256 + threadIdx.x;   // 0..360447
    const float* src; int K, lgC, local; size_t oh, ol;
    if (idx < 32768)        { src = Wm;  K = 256; lgC = 7; local = idx;          oh = OFF_WM_H;  ol = OFF_WM_L; }
    else if (idx < 49152)   { src = Wk;  K = 256; lgC = 6; local = idx - 32768;  oh = OFF_WK_H;  ol = OFF_WK_L; }
    else if (idx < 65536)   { src = Wq;  K = 256; lgC = 6; local = idx - 49152;  oh = OFF_WQ_H;  ol = OFF_WQ_L; }
    else if (idx < 98304)   { src = Wir; K = 128; lgC = 8; local = idx - 65536;  oh = OFF_WIR_H; ol = OFF_WIR_L; }
    else if (idx < 131072)  { src = Wiz; K = 128; lgC = 8; local = idx - 98304;  oh = OFF_WIZ_H; ol = OFF_WIZ_L; }
    else if (idx < 163840)  { src = Win; K = 128; lgC = 8; local = idx - 131072; oh = OFF_WIN_H; ol = OFF_WIN_L; }
    else if (idx < 229376)  { src = Whr; K = 256; lgC = 8; local = idx - 163840; oh = OFF_WHR_H; ol = OFF_WHR_L; }
    else if (idx < 294912)  { src = Whz; K = 256; lgC = 8; local = idx - 229376; oh = OFF_WHZ_H; ol = OFF_WHZ_L; }
    else if (idx < 360448)  { src = Whn; K = 256; lgC = 8; local = idx - 294912; oh = OFF_WHN_H; ol = OFF_WHN_L; }
    else return;
    int k = local >> lgC, c = local & ((1 << lgC) - 1);   // src row-major [k][c]
    float v = src[local];
    short hi = f2bf(v);
    short lo = f2bf(v - bf2f(hi));
    wT[oh + (size_t)c * K + k] = hi;
    wT[ol + (size_t)c * K + k] = lo;
}

// ---------------- Kernel A: projections via MFMA (hi/lo x hi/lo) --------------
// 512 blocks x 16 rows; 4 waves: waves 0,1 -> msg cols, wave 2 -> key, wave 3 -> qry
__global__ __launch_bounds__(256) void proj_mfma_kernel(
    const float* __restrict__ h, const short* __restrict__ wT,
    const float* __restrict__ bm, const float* __restrict__ bk, const float* __restrict__ bq,
    short* __restrict__ msgTb,
    short* __restrict__ qh, short* __restrict__ ql,
    short* __restrict__ kh, short* __restrict__ kl)
{
    __shared__ short hh[16][264], hl[16][264];   // +8 pad
    int t = threadIdx.x;
    int wave = t >> 6, l = t & 63, quad = l >> 4, ln = l & 15;
    int i0 = blockIdx.x * 16;

    // stage h rows -> hi/lo LDS (16 x 256 f32)
#pragma unroll
    for (int p = 0; p < 4; p++) {
        int idx = t + p * 256;           // 0..1023 float4s
        int r = idx >> 6, k4 = (idx & 63) * 4;
        float4 v = *(const float4*)&h[(size_t)(i0 + r) * HIDDEN + k4];
        short4_t hv, lv;
        split4(v, &hv, &lv);
        *(short4_t*)&hh[r][k4] = hv;
        *(short4_t*)&hl[r][k4] = lv;
    }
    __syncthreads();

    size_t base_h, base_l; int cb;
    if (wave < 2)      { base_h = OFF_WM_H; base_l = OFF_WM_L; cb = wave * 64; }
    else if (wave == 2){ base_h = OFF_WK_H; base_l = OFF_WK_L; cb = 0; }
    else               { base_h = OFF_WQ_H; base_l = OFF_WQ_L; cb = 0; }

    float4_t acc[4];
#pragma unroll
    for (int nt = 0; nt < 4; nt++) acc[nt] = (float4_t)0.f;

    for (int ch = 0; ch < 8; ch++) {
        short8_t a_h = *(short8_t*)&hh[ln][ch * 32 + quad * 8];
        short8_t a_l = *(short8_t*)&hl[ln][ch * 32 + quad * 8];
#pragma unroll
        for (int nt = 0; nt < 4; nt++) {
            int c = cb + nt * 16 + ln;
            const short* bp_h = wT + base_h + (size_t)c * 256 + ch * 32 + quad * 8;
            const short* bp_l = wT + base_l + (size_t)c * 256 + ch * 32 + quad * 8;
            short8_t b_h = *(const short8_t*)bp_h;
            short8_t b_l = *(const short8_t*)bp_l;
            acc[nt] = __builtin_amdgcn_mfma_f32_16x16x32_bf16(a_h, b_h, acc[nt], 0, 0, 0);
            acc[nt] = __builtin_amdgcn_mfma_f32_16x16x32_bf16(a_h, b_l, acc[nt], 0, 0, 0);
            acc[nt] = __builtin_amdgcn_mfma_f32_16x16x32_bf16(a_l, b_h, acc[nt], 0, 0, 0);
        }
    }

    if (wave < 2) {
#pragma unroll
        for (int nt = 0; nt < 4; nt++) {
            int col = cb + nt * 16 + ln;
            float b = bm[col];
            short4_t o;
#pragma unroll
            for (int reg = 0; reg < 4; reg++) o[reg] = f2bf(acc[nt][reg] + b);
            *(short4_t*)&msgTb[(size_t)col * N_AGENTS + i0 + quad * 4] = o;
        }
    } else {
        short* dh = (wave == 2) ? kh : qh;
        short* dl = (wave == 2) ? kl : ql;
        const float* bias = (wave == 2) ? bk : bq;
#pragma unroll
        for (int nt = 0; nt < 4; nt++) {
            int col = nt * 16 + ln;
            float b = bias[col];
#pragma unroll
            for (int reg = 0; reg < 4; reg++) {
                int row = i0 + quad * 4 + reg;
                float v = acc[nt][reg] + b;
                short hi = f2bf(v);
                short lo = f2bf(v - bf2f(hi));
                dh[(size_t)row * KEYD + col] = hi;
                dl[(size_t)row * KEYD + col] = lo;
            }
        }
    }
}

// ---------- Kernel B1: MFMA scores -> exp -> row sums only (NO P write) -------
__global__ __launch_bounds__(256) void rowsum_kernel(
    const short* __restrict__ qh, const short* __restrict__ ql,
    const short* __restrict__ kh, const short* __restrict__ kl,
    float* __restrict__ rowsum)
{
    int t = threadIdx.x;
    int wave = t >> 6, l = t & 63;
    int quad = l >> 4, ln = l & 15;
    int i0 = blockIdx.y * 64;
    int j0 = blockIdx.x * 256 + wave * 64;

    short8_t ah[4][2], al[4][2];
#pragma unroll
    for (int r = 0; r < 4; r++)
#pragma unroll
        for (int ch = 0; ch < 2; ch++) {
            size_t off = (size_t)(i0 + r * 16 + ln) * KEYD + ch * 32 + quad * 8;
            ah[r][ch] = *(const short8_t*)(qh + off);
            al[r][ch] = *(const short8_t*)(ql + off);
        }

    float4_t acc[4][4];
#pragma unroll
    for (int r = 0; r < 4; r++)
#pragma unroll
        for (int c = 0; c < 4; c++) acc[r][c] = (float4_t)0.f;

#pragma unroll
    for (int c = 0; c < 4; c++) {
        int coln = j0 + c * 16 + ln;
#pragma unroll
        for (int ch = 0; ch < 2; ch++) {
            size_t off = (size_t)coln * KEYD + ch * 32 + quad * 8;
            short8_t bh = *(const short8_t*)(kh + off);
            short8_t bl = *(const short8_t*)(kl + off);
#pragma unroll
            for (int r = 0; r < 4; r++) {
                acc[r][c] = __builtin_amdgcn_mfma_f32_16x16x32_bf16(ah[r][ch], bh, acc[r][c], 0, 0, 0);
                acc[r][c] = __builtin_amdgcn_mfma_f32_16x16x32_bf16(ah[r][ch], bl, acc[r][c], 0, 0, 0);
                acc[r][c] = __builtin_amdgcn_mfma_f32_16x16x32_bf16(al[r][ch], bh, acc[r][c], 0, 0, 0);
            }
        }
    }

    float prow[4][4];
#pragma unroll
    for (int r = 0; r < 4; r++)
#pragma unroll
        for (int reg = 0; reg < 4; reg++) {
            int gi = i0 + r * 16 + quad * 4 + reg;
            float sum = 0.f;
#pragma unroll
            for (int c = 0; c < 4; c++) {
                float s = acc[r][c][reg] * 0.125f;
                s = fminf(fmaxf(s, -20.f), 20.f);
                int gj = j0 + c * 16 + ln;
                float p = (gi == gj) ? 0.f : __expf(s);
                sum += p;
            }
            prow[r][reg] = sum;
        }

#pragma unroll
    for (int off = 1; off < 16; off <<= 1)
#pragma unroll
        for (int r = 0; r < 4; r++)
#pragma unroll
            for (int reg = 0; reg < 4; reg++)
                prow[r][reg] += __shfl_xor(prow[r][reg], off);

    if (ln == 0) {
#pragma unroll
        for (int r = 0; r < 4; r++)
#pragma unroll
            for (int reg = 0; reg < 4; reg++)
                atomicAdd(&rowsum[i0 + r * 16 + quad * 4 + reg], prow[r][reg]);
    }
}

// ---- Kernel B2: recompute scores -> write NORMALIZED P once -> fused P@msg ---
// Per 128-col step:
//   score MFMA (global k, L2) -> barrier1 -> stage msgT + epilogue (exp/normalize
//   -> p regs + A_lds) + B_lds -> barrier2 -> P stores (retire under PV + next
//   score, ~500+ cyc slack before the next vmcnt(0) drain) + PV MFMA.
// No atomics: each block writes its own att_part slice; gru sums the 4 slices.
__global__ __launch_bounds__(256) void attend_fused_kernel(
    const short* __restrict__ qh, const short* __restrict__ ql,
    const short* __restrict__ kh, const short* __restrict__ kl,
    const short* __restrict__ msgTb, const float* __restrict__ rowsum,
    float* __restrict__ P, float* __restrict__ att_part)
{
    const int JB = 128;
    const int STR = JB + 8;            // 136 shorts: 272 B row stride, 16B-aligned
    __shared__ short A_lds[64][STR];   // normalized P tile, bf16
    __shared__ short B_lds[MSG][STR];  // msgT tile [col][k]
    __shared__ float inv_s[64];

    int t = threadIdx.x;
    int wave = t >> 6, l = t & 63;
    int quad = l >> 4, ln = l & 15;
    int i0 = blockIdx.y * 64;
    int kbase = blockIdx.x * (N_AGENTS / CSPLIT);

    if (t < 64) inv_s[t] = 1.0f / rowsum[i0 + t];

    // Q fragments: loaded once, reused across all steps
    short8_t ah[4][2], al[4][2];
#pragma unroll
    for (int r = 0; r < 4; r++)
#pragma unroll
        for (int ch = 0; ch < 2; ch++) {
            size_t off = (size_t)(i0 + r * 16 + ln) * KEYD + ch * 32 + quad * 8;
            ah[r][ch] = *(const short8_t*)(qh + off);
            al[r][ch] = *(const short8_t*)(ql + off);
        }

    float4_t accm[8];
#pragma unroll
    for (int c = 0; c < 8; c++) accm[c] = (float4_t)0.f;

    __syncthreads();

    for (int jt = 0; jt < N_AGENTS / CSPLIT; jt += JB) {
        int kpos = kbase + jt;

        // ---- scores (registers only; same FP sequence as rowsum_kernel) ----
        float4_t acc[4][2];
#pragma unroll
        for (int r = 0; r < 4; r++)
#pragma unroll
            for (int c2 = 0; c2 < 2; c2++) acc[r][c2] = (float4_t)0.f;

#pragma unroll
        for (int c2 = 0; c2 < 2; c2++) {
            int coln = kpos + wave * 32 + c2 * 16 + ln;
#pragma unroll
            for (int ch = 0; ch < 2; ch++) {
                size_t off = (size_t)coln * KEYD + ch * 32 + quad * 8;
                short8_t bh = *(const short8_t*)(kh + off);
                short8_t bl = *(const short8_t*)(kl + off);
#pragma unroll
                for (int r = 0; r < 4; r++) {
                    acc[r][c2] = __builtin_amdgcn_mfma_f32_16x16x32_bf16(ah[r][ch], bh, acc[r][c2], 0, 0, 0);
                    acc[r][c2] = __builtin_amdgcn_mfma_f32_16x16x32_bf16(ah[r][ch], bl, acc[r][c2], 0, 0, 0);
                    acc[r][c2] = __builtin_amdgcn_mfma_f32_16x16x32_bf16(al[r][ch], bh, acc[r][c2], 0, 0, 0);
                }
            }
        }

        __syncthreads();   // previous step's PV reads of LDS + P stores drained

        // ---- stage msgT tile into regs (latency overlaps epilogue VALU) ----
        short8_t bst[8];
#pragma unroll
        for (int p = 0; p < 8; p++) {
            int idx = t + p * 256;         // 0..2047
            int c = idx >> 4, kk = (idx & 15) * 8;
            bst[p] = *(const short8_t*)(msgTb + (size_t)c * N_AGENTS + kpos + kk);
        }

        // ---- epilogue: normalize -> p regs + LDS stash (NO global stores) ----
        float pv[4][4][2];
#pragma unroll
        for (int r = 0; r < 4; r++)
#pragma unroll
            for (int reg = 0; reg < 4; reg++) {
                int row = r * 16 + quad * 4 + reg;
                int gi = i0 + row;
                float iv = inv_s[row];
#pragma unroll
                for (int c2 = 0; c2 < 2; c2++) {
                    int col = wave * 32 + c2 * 16 + ln;
                    int gj = kpos + col;
                    float s = acc[r][c2][reg] * 0.125f;
                    s = fminf(fmaxf(s, -20.f), 20.f);
                    float p = (gi == gj) ? 0.f : __expf(s) * iv;
                    pv[r][reg][c2] = p;
                    A_lds[row][col] = f2bf(p);
                }
            }

        // ---- msgT regs -> LDS ----
#pragma unroll
        for (int p = 0; p < 8; p++) {
            int idx = t + p * 256;
            int c = idx >> 4, kk = (idx & 15) * 8;
            *(short8_t*)&B_lds[c][kk] = bst[p];
        }

        __syncthreads();   // A_lds + B_lds ready

        // ---- P stores: issued here, retire under PV + next score ----
#pragma unroll
        for (int r = 0; r < 4; r++)
#pragma unroll
            for (int reg = 0; reg < 4; reg++) {
                int gi = i0 + r * 16 + quad * 4 + reg;
#pragma unroll
                for (int c2 = 0; c2 < 2; c2++) {
                    int gj = kpos + wave * 32 + c2 * 16 + ln;
                    __builtin_nontemporal_store(pv[r][reg][c2], &P[(size_t)gi * N_AGENTS + gj]);
                }
            }

        // ---- PV: accm += P_tile @ msgT_tile (k = 128 this step) ----
#pragma unroll
        for (int kc = 0; kc < 4; kc++) {
            short8_t a = *(short8_t*)&A_lds[wave * 16 + ln][kc * 32 + quad * 8];
#pragma unroll
            for (int c = 0; c < 8; c++) {
                short8_t b = *(short8_t*)&B_lds[c * 16 + ln][kc * 32 + quad * 8];
                accm[c] = __builtin_amdgcn_mfma_f32_16x16x32_bf16(a, b, accm[c], 0, 0, 0);
            }
        }
    }

    // ---- per-slice partial output (no atomics; block owns these rows) ----
    float* ap = att_part + (size_t)blockIdx.x * N_AGENTS * MSG;
#pragma unroll
    for (int c = 0; c < 8; c++)
#pragma unroll
        for (int reg = 0; reg < 4; reg++) {
            int row = i0 + wave * 16 + quad * 4 + reg;
            int col = c * 16 + ln;
            ap[(size_t)row * MSG + col] = accm[c][reg];
        }
}

// ---------------- Kernel D: GRU cell via MFMA (hi/lo x hi/lo) -----------------
// Stages att by summing the CSPLIT partial slices.
__global__ __launch_bounds__(256) void gru_mfma_kernel(
    const float* __restrict__ att_part, const float* __restrict__ h,
    const short* __restrict__ wT,
    const float* __restrict__ bir, const float* __restrict__ biz,
    const float* __restrict__ bin, const float* __restrict__ bhn,
    float* __restrict__ hnew)
{
    __shared__ short ath[16][136], atl[16][136];  // att hi/lo
    __shared__ short hh[16][264], hl[16][264];    // h hi/lo
    int t = threadIdx.x;
    int wave = t >> 6, l = t & 63, quad = l >> 4, ln = l & 15;
    int i0 = blockIdx.x * 16;
    int cb = wave * 64;

    // stage att (16 x 128 f32) = sum of CSPLIT partial slices
#pragma unroll
    for (int p = 0; p < 2; p++) {
        int idx = t + p * 256;           // 0..511 float4s
        int r = idx >> 5, c4 = (idx & 31) * 4;
        size_t off = (size_t)(i0 + r) * MSG + c4;
        float4 v = *(const float4*)&att_part[off];
#pragma unroll
        for (int s = 1; s < CSPLIT; s++) {
            float4 w = *(const float4*)&att_part[(size_t)s * N_AGENTS * MSG + off];
            v.x += w.x; v.y += w.y; v.z += w.z; v.w += w.w;
        }
        short4_t hv, lv;
        split4(v, &hv, &lv);
        *(short4_t*)&ath[r][c4] = hv;
        *(short4_t*)&atl[r][c4] = lv;
    }
    // stage h (16 x 256 f32)
#pragma unroll
    for (int p = 0; p < 4; p++) {
        int idx = t + p * 256;           // 0..1023 float4s
        int r = idx >> 6, k4 = (idx & 63) * 4;
        float4 v = *(const float4*)&h[(size_t)(i0 + r) * HIDDEN + k4];
        short4_t hv, lv;
        split4(v, &hv, &lv);
        *(short4_t*)&hh[r][k4] = hv;
        *(short4_t*)&hl[r][k4] = lv;
    }
    __syncthreads();

    float4_t ar[4], az[4], an[4], hn[4];
#pragma unroll
    for (int nt = 0; nt < 4; nt++) {
        ar[nt] = (float4_t)0.f; az[nt] = (float4_t)0.f;
        an[nt] = (float4_t)0.f; hn[nt] = (float4_t)0.f;
    }

#define MFMA3(ACC, AH, AL, BH, BL)                                              \
    ACC = __builtin_amdgcn_mfma_f32_16x16x32_bf16(AH, BH, ACC, 0, 0, 0);        \
    ACC = __builtin_amdgcn_mfma_f32_16x16x32_bf16(AH, BL, ACC, 0, 0, 0);        \
    ACC = __builtin_amdgcn_mfma_f32_16x16x32_bf16(AL, BH, ACC, 0, 0, 0);

    // att @ Wi_{r,z,n} : K = 128, 4 chunks
    for (int ch = 0; ch < 4; ch++) {
        short8_t a_h = *(short8_t*)&ath[ln][ch * 32 + quad * 8];
        short8_t a_l = *(short8_t*)&atl[ln][ch * 32 + quad * 8];
#pragma unroll
        for (int nt = 0; nt < 4; nt++) {
            size_t cw = (size_t)(cb + nt * 16 + ln) * 128 + ch * 32 + quad * 8;
            short8_t brh = *(const short8_t*)(wT + OFF_WIR_H + cw);
            short8_t brl = *(const short8_t*)(wT + OFF_WIR_L + cw);
            MFMA3(ar[nt], a_h, a_l, brh, brl);
            short8_t bzh = *(const short8_t*)(wT + OFF_WIZ_H + cw);
            short8_t bzl = *(const short8_t*)(wT + OFF_WIZ_L + cw);
            MFMA3(az[nt], a_h, a_l, bzh, bzl);
            short8_t bnh = *(const short8_t*)(wT + OFF_WIN_H + cw);
            short8_t bnl = *(const short8_t*)(wT + OFF_WIN_L + cw);
            MFMA3(an[nt], a_h, a_l, bnh, bnl);
        }
    }

    // h @ Wh_{r,z,n} : K = 256, 8 chunks
    for (int ch = 0; ch < 8; ch++) {
        short8_t a_h = *(short8_t*)&hh[ln][ch * 32 + quad * 8];
        short8_t a_l = *(short8_t*)&hl[ln][ch * 32 + quad * 8];
#pragma unroll
        for (int nt = 0; nt < 4; nt++) {
            size_t cw = (size_t)(cb + nt * 16 + ln) * 256 + ch * 32 + quad * 8;
            short8_t brh = *(const short8_t*)(wT + OFF_WHR_H + cw);
            short8_t brl = *(const short8_t*)(wT + OFF_WHR_L + cw);
            MFMA3(ar[nt], a_h, a_l, brh, brl);
            short8_t bzh = *(const short8_t*)(wT + OFF_WHZ_H + cw);
            short8_t bzl = *(const short8_t*)(wT + OFF_WHZ_L + cw);
            MFMA3(az[nt], a_h, a_l, bzh, bzl);
            short8_t bnh = *(const short8_t*)(wT + OFF_WHN_H + cw);
            short8_t bnl = *(const short8_t*)(wT + OFF_WHN_L + cw);
            MFMA3(hn[nt], a_h, a_l, bnh, bnl);
        }
    }
#undef MFMA3

    // epilogue: gates + blend (fp32)
#pragma unroll
    for (int nt = 0; nt < 4; nt++) {
        int col = cb + nt * 16 + ln;
        float br = bir[col], bz = biz[col], bn = bin[col], bh_ = bhn[col];
#pragma unroll
        for (int reg = 0; reg < 4; reg++) {
            int row = i0 + quad * 4 + reg;
            float hv = h[(size_t)row * HIDDEN + col];
            float rr = 1.f / (1.f + __expf(-(ar[nt][reg] + br)));
            float zz = 1.f / (1.f + __expf(-(az[nt][reg] + bz)));
            float cand = tanhf(an[nt][reg] + bn + rr * (hn[nt][reg] + bh_));
            hnew[(size_t)row * HIDDEN + col] = (1.f - zz) * cand + zz * hv;
        }
    }
}

// ---------------- launch ------------------------------------------------------
extern "C" void kernel_launch(void* const* d_in, const int* in_sizes, int n_in,
                              void* d_out, int out_size, void* d_ws, size_t ws_size,
                              hipStream_t stream)
{
    const float* h     = (const float*)d_in[0];
    const float* W_msg = (const float*)d_in[1];
    const float* b_msg = (const float*)d_in[2];
    const float* W_key = (const float*)d_in[3];
    const float* b_key = (const float*)d_in[4];
    const float* W_qry = (const float*)d_in[5];
    const float* b_qry = (const float*)d_in[6];
    const float* Wi_r  = (const float*)d_in[7];
    const float* bi_r  = (const float*)d_in[8];
    const float* Wi_z  = (const float*)d_in[9];
    const float* bi_z  = (const float*)d_in[10];
    const float* Wi_n  = (const float*)d_in[11];
    const float* bi_n  = (const float*)d_in[12];
    const float* Wh_r  = (const float*)d_in[13];
    const float* Wh_z  = (const float*)d_in[14];
    const float* Wh_n  = (const float*)d_in[15];
    const float* bh_n  = (const float*)d_in[16];

    float* out  = (float*)d_out;
    float* hnew = out;                                   // [8192,256]
    float* P    = out + (size_t)N_AGENTS * HIDDEN;       // attn region [8192,8192]

    float* ws       = (float*)d_ws;
    float* rowsum   = ws;                                  // 8192 f32
    float* att_part = ws + N_AGENTS;                       // CSPLIT * 8192*128 f32
    short* sbase    = (short*)(att_part + (size_t)CSPLIT * N_AGENTS * MSG);
    short* msgTb    = sbase;                               // 128*8192 bf16
    short* qh       = msgTb + (size_t)MSG * N_AGENTS;      // 8192*64
    short* ql       = qh + (size_t)N_AGENTS * KEYD;
    short* kh       = ql + (size_t)N_AGENTS * KEYD;
    short* kl       = kh + (size_t)N_AGENTS * KEYD;
    short* wT       = kl + (size_t)N_AGENTS * KEYD;        // 720896 shorts

    // zero rowsum only (att_part is fully overwritten, no atomics)
    hipMemsetAsync(rowsum, 0, (size_t)N_AGENTS * sizeof(float), stream);

    prep_weights<<<1408, 256, 0, stream>>>(W_msg, W_key, W_qry, Wi_r, Wi_z, Wi_n,
                                           Wh_r, Wh_z, Wh_n, wT);

    proj_mfma_kernel<<<N_AGENTS / 16, 256, 0, stream>>>(h, wT, b_msg, b_key, b_qry,
                                                        msgTb, qh, ql, kh, kl);

    rowsum_kernel<<<dim3(N_AGENTS / 256, N_AGENTS / 64), 256, 0, stream>>>(qh, ql, kh, kl, rowsum);

    attend_fused_kernel<<<dim3(CSPLIT, N_AGENTS / 64), 256, 0, stream>>>(qh, ql, kh, kl,
                                                                         msgTb, rowsum, P, att_part);

    gru_mfma_kernel<<<N_AGENTS / 16, 256, 0, stream>>>(att_part, h, wT, bi_r, bi_z, bi_n, bh_n, hnew);
}

// Round 5
// 528.228 us; speedup vs baseline: 1.5847x; 1.1280x over previous
//
#include <hip/hip_runtime.h>
#include <math.h>

#define N_AGENTS 8192
#define HIDDEN   256
#define MSG      128
#define KEYD     64
#define CSPLIT   4
#define NSTEP    (N_AGENTS / CSPLIT / 64)   // 32

// ---- transposed hi/lo bf16 weight cache layout (shorts, in workspace) -------
#define OFF_WM_H   0        // [128][256]
#define OFF_WM_L   32768
#define OFF_WK_H   65536    // [64][256]
#define OFF_WK_L   81920
#define OFF_WQ_H   98304
#define OFF_WQ_L   114688
#define OFF_WIR_H  131072   // [256][128]
#define OFF_WIR_L  163840
#define OFF_WIZ_H  196608
#define OFF_WIZ_L  229376
#define OFF_WIN_H  262144
#define OFF_WIN_L  294912
#define OFF_WHR_H  327680   // [256][256]
#define OFF_WHR_L  393216
#define OFF_WHZ_H  458752
#define OFF_WHZ_L  524288
#define OFF_WHN_H  589824
#define OFF_WHN_L  655360
#define WT_TOTAL   720896

typedef __attribute__((ext_vector_type(8))) short short8_t;
typedef __attribute__((ext_vector_type(4))) short short4_t;
typedef __attribute__((ext_vector_type(4))) float float4_t;

__device__ __forceinline__ short f2bf(float x) {
    unsigned u = __float_as_uint(x);
    unsigned r = (u + 0x7fffu + ((u >> 16) & 1u)) >> 16;
    return (short)r;
}
__device__ __forceinline__ float bf2f(short b) {
    return __uint_as_float(((unsigned)(unsigned short)b) << 16);
}
__device__ __forceinline__ void split4(float4 v, short4_t* hi, short4_t* lo) {
    (*hi)[0] = f2bf(v.x); (*lo)[0] = f2bf(v.x - bf2f((*hi)[0]));
    (*hi)[1] = f2bf(v.y); (*lo)[1] = f2bf(v.y - bf2f((*hi)[1]));
    (*hi)[2] = f2bf(v.z); (*lo)[2] = f2bf(v.z - bf2f((*hi)[2]));
    (*hi)[3] = f2bf(v.w); (*lo)[3] = f2bf(v.w - bf2f((*hi)[3]));
}

// ---------- Kernel P0: weights -> transposed hi/lo bf16 (runs once) -----------
__global__ __launch_bounds__(256) void prep_weights(
    const float* __restrict__ Wm, const float* __restrict__ Wk, const float* __restrict__ Wq,
    const float* __restrict__ Wir, const float* __restrict__ Wiz, const float* __restrict__ Win,
    const float* __restrict__ Whr, const float* __restrict__ Whz, const float* __restrict__ Whn,
    short* __restrict__ wT)
{
    int idx = blockIdx.x * 256 + threadIdx.x;   // 0..360447
    const float* src; int K, lgC, local; size_t oh, ol;
    if (idx < 32768)        { src = Wm;  K = 256; lgC = 7; local = idx;          oh = OFF_WM_H;  ol = OFF_WM_L; }
    else if (idx < 49152)   { src = Wk;  K = 256; lgC = 6; local = idx - 32768;  oh = OFF_WK_H;  ol = OFF_WK_L; }
    else if (idx < 65536)   { src = Wq;  K = 256; lgC = 6; local = idx - 49152;  oh = OFF_WQ_H;  ol = OFF_WQ_L; }
    else if (idx < 98304)   { src = Wir; K = 128; lgC = 8; local = idx - 65536;  oh = OFF_WIR_H; ol = OFF_WIR_L; }
    else if (idx < 131072)  { src = Wiz; K = 128; lgC = 8; local = idx - 98304;  oh = OFF_WIZ_H; ol = OFF_WIZ_L; }
    else if (idx < 163840)  { src = Win; K = 128; lgC = 8; local = idx - 131072; oh = OFF_WIN_H; ol = OFF_WIN_L; }
    else if (idx < 229376)  { src = Whr; K = 256; lgC = 8; local = idx - 163840; oh = OFF_WHR_H; ol = OFF_WHR_L; }
    else if (idx < 294912)  { src = Whz; K = 256; lgC = 8; local = idx - 229376; oh = OFF_WHZ_H; ol = OFF_WHZ_L; }
    else if (idx < 360448)  { src = Whn; K = 256; lgC = 8; local = idx - 294912; oh = OFF_WHN_H; ol = OFF_WHN_L; }
    else return;
    int k = local >> lgC, c = local & ((1 << lgC) - 1);   // src row-major [k][c]
    float v = src[local];
    short hi = f2bf(v);
    short lo = f2bf(v - bf2f(hi));
    wT[oh + (size_t)c * K + k] = hi;
    wT[ol + (size_t)c * K + k] = lo;
}

// ---------------- Kernel A: projections via MFMA (hi/lo x hi/lo) --------------
__global__ __launch_bounds__(256) void proj_mfma_kernel(
    const float* __restrict__ h, const short* __restrict__ wT,
    const float* __restrict__ bm, const float* __restrict__ bk, const float* __restrict__ bq,
    short* __restrict__ msgTb,
    short* __restrict__ qh, short* __restrict__ ql,
    short* __restrict__ kh, short* __restrict__ kl)
{
    __shared__ short hh[16][264], hl[16][264];   // +8 pad
    int t = threadIdx.x;
    int wave = t >> 6, l = t & 63, quad = l >> 4, ln = l & 15;
    int i0 = blockIdx.x * 16;

#pragma unroll
    for (int p = 0; p < 4; p++) {
        int idx = t + p * 256;           // 0..1023 float4s
        int r = idx >> 6, k4 = (idx & 63) * 4;
        float4 v = *(const float4*)&h[(size_t)(i0 + r) * HIDDEN + k4];
        short4_t hv, lv;
        split4(v, &hv, &lv);
        *(short4_t*)&hh[r][k4] = hv;
        *(short4_t*)&hl[r][k4] = lv;
    }
    __syncthreads();

    size_t base_h, base_l; int cb;
    if (wave < 2)      { base_h = OFF_WM_H; base_l = OFF_WM_L; cb = wave * 64; }
    else if (wave == 2){ base_h = OFF_WK_H; base_l = OFF_WK_L; cb = 0; }
    else               { base_h = OFF_WQ_H; base_l = OFF_WQ_L; cb = 0; }

    float4_t acc[4];
#pragma unroll
    for (int nt = 0; nt < 4; nt++) acc[nt] = (float4_t)0.f;

    for (int ch = 0; ch < 8; ch++) {
        short8_t a_h = *(short8_t*)&hh[ln][ch * 32 + quad * 8];
        short8_t a_l = *(short8_t*)&hl[ln][ch * 32 + quad * 8];
#pragma unroll
        for (int nt = 0; nt < 4; nt++) {
            int c = cb + nt * 16 + ln;
            short8_t b_h = *(const short8_t*)(wT + base_h + (size_t)c * 256 + ch * 32 + quad * 8);
            short8_t b_l = *(const short8_t*)(wT + base_l + (size_t)c * 256 + ch * 32 + quad * 8);
            acc[nt] = __builtin_amdgcn_mfma_f32_16x16x32_bf16(a_h, b_h, acc[nt], 0, 0, 0);
            acc[nt] = __builtin_amdgcn_mfma_f32_16x16x32_bf16(a_h, b_l, acc[nt], 0, 0, 0);
            acc[nt] = __builtin_amdgcn_mfma_f32_16x16x32_bf16(a_l, b_h, acc[nt], 0, 0, 0);
        }
    }

    if (wave < 2) {
#pragma unroll
        for (int nt = 0; nt < 4; nt++) {
            int col = cb + nt * 16 + ln;
            float b = bm[col];
            short4_t o;
#pragma unroll
            for (int reg = 0; reg < 4; reg++) o[reg] = f2bf(acc[nt][reg] + b);
            *(short4_t*)&msgTb[(size_t)col * N_AGENTS + i0 + quad * 4] = o;
        }
    } else {
        short* dh = (wave == 2) ? kh : qh;
        short* dl = (wave == 2) ? kl : ql;
        const float* bias = (wave == 2) ? bk : bq;
#pragma unroll
        for (int nt = 0; nt < 4; nt++) {
            int col = nt * 16 + ln;
            float b = bias[col];
#pragma unroll
            for (int reg = 0; reg < 4; reg++) {
                int row = i0 + quad * 4 + reg;
                float v = acc[nt][reg] + b;
                short hi = f2bf(v);
                short lo = f2bf(v - bf2f(hi));
                dh[(size_t)row * KEYD + col] = hi;
                dl[(size_t)row * KEYD + col] = lo;
            }
        }
    }
}

// ---------- Kernel B1: MFMA scores -> exp -> partial row sums (no atomics) ----
// rowsum_part layout: [row][128], partial p = blockIdx.x*4 + wave.
__global__ __launch_bounds__(256) void rowsum_kernel(
    const short* __restrict__ qh, const short* __restrict__ ql,
    const short* __restrict__ kh, const short* __restrict__ kl,
    float* __restrict__ rowsum_part)
{
    int t = threadIdx.x;
    int wave = t >> 6, l = t & 63;
    int quad = l >> 4, ln = l & 15;
    int i0 = blockIdx.y * 64;
    int j0 = blockIdx.x * 256 + wave * 64;

    short8_t ah[4][2], al[4][2];
#pragma unroll
    for (int r = 0; r < 4; r++)
#pragma unroll
        for (int ch = 0; ch < 2; ch++) {
            size_t off = (size_t)(i0 + r * 16 + ln) * KEYD + ch * 32 + quad * 8;
            ah[r][ch] = *(const short8_t*)(qh + off);
            al[r][ch] = *(const short8_t*)(ql + off);
        }

    float4_t acc[4][4];
#pragma unroll
    for (int r = 0; r < 4; r++)
#pragma unroll
        for (int c = 0; c < 4; c++) acc[r][c] = (float4_t)0.f;

#pragma unroll
    for (int c = 0; c < 4; c++) {
        int coln = j0 + c * 16 + ln;
#pragma unroll
        for (int ch = 0; ch < 2; ch++) {
            size_t off = (size_t)coln * KEYD + ch * 32 + quad * 8;
            short8_t bh = *(const short8_t*)(kh + off);
            short8_t bl = *(const short8_t*)(kl + off);
#pragma unroll
            for (int r = 0; r < 4; r++) {
                acc[r][c] = __builtin_amdgcn_mfma_f32_16x16x32_bf16(ah[r][ch], bh, acc[r][c], 0, 0, 0);
                acc[r][c] = __builtin_amdgcn_mfma_f32_16x16x32_bf16(ah[r][ch], bl, acc[r][c], 0, 0, 0);
                acc[r][c] = __builtin_amdgcn_mfma_f32_16x16x32_bf16(al[r][ch], bh, acc[r][c], 0, 0, 0);
            }
        }
    }

    float prow[4][4];
#pragma unroll
    for (int r = 0; r < 4; r++)
#pragma unroll
        for (int reg = 0; reg < 4; reg++) {
            int gi = i0 + r * 16 + quad * 4 + reg;
            float sum = 0.f;
#pragma unroll
            for (int c = 0; c < 4; c++) {
                float s = acc[r][c][reg] * 0.125f;
                s = fminf(fmaxf(s, -20.f), 20.f);
                int gj = j0 + c * 16 + ln;
                float p = (gi == gj) ? 0.f : __expf(s);
                sum += p;
            }
            prow[r][reg] = sum;
        }

#pragma unroll
    for (int off = 1; off < 16; off <<= 1)
#pragma unroll
        for (int r = 0; r < 4; r++)
#pragma unroll
            for (int reg = 0; reg < 4; reg++)
                prow[r][reg] += __shfl_xor(prow[r][reg], off);

    if (ln == 0) {
        int pidx = blockIdx.x * 4 + wave;
#pragma unroll
        for (int r = 0; r < 4; r++)
#pragma unroll
            for (int reg = 0; reg < 4; reg++)
                rowsum_part[(size_t)(i0 + r * 16 + quad * 4 + reg) * 128 + pidx] = prow[r][reg];
    }
}

// ---- Kernel B2: 1-barrier/step double-buffered fused score+P-write+PV --------
// JB=64, 32 steps. Per step: epilogue(st)->A_lds[buf], bst->B_lds[buf], barrier,
// P stores issue, prefetch K/msgT(st+1), PV MFMA(st), score MFMA(st+1).
// Score/PV accumulation order bit-identical to previous version.
__global__ __launch_bounds__(256, 2) void attend_fused_kernel(
    const short* __restrict__ qh, const short* __restrict__ ql,
    const short* __restrict__ kh, const short* __restrict__ kl,
    const short* __restrict__ msgTb, const float* __restrict__ rowsum_part,
    float* __restrict__ P, float* __restrict__ att_part)
{
    __shared__ short A_lds[2][64][72];    // P tile bf16, dbuf
    __shared__ short B_lds[2][128][72];   // msgT tile, dbuf
    __shared__ float inv_s[64];

    int t = threadIdx.x;
    int wave = t >> 6, l = t & 63;
    int quad = l >> 4, ln = l & 15;
    int i0 = blockIdx.y * 64;
    int kbase = blockIdx.x * (N_AGENTS / CSPLIT);

    // 1/rowsum from 128 partials
    if (t < 64) {
        const float* rp = rowsum_part + (size_t)(i0 + t) * 128;
        float s = 0.f;
#pragma unroll
        for (int p = 0; p < 32; p++) {
            float4 v = *(const float4*)(rp + p * 4);
            s += v.x + v.y + v.z + v.w;
        }
        inv_s[t] = 1.0f / s;
    }

    // Q fragments (persist all steps)
    short8_t ah[4][2], al[4][2];
#pragma unroll
    for (int r = 0; r < 4; r++)
#pragma unroll
        for (int ch = 0; ch < 2; ch++) {
            size_t off = (size_t)(i0 + r * 16 + ln) * KEYD + ch * 32 + quad * 8;
            ah[r][ch] = *(const short8_t*)(qh + off);
            al[r][ch] = *(const short8_t*)(ql + off);
        }

    float4_t accm[8];
#pragma unroll
    for (int c = 0; c < 8; c++) accm[c] = (float4_t)0.f;

    const int colL = wave * 16 + ln;

    // ---- prologue: load step-0 K-frags + msgT, compute score(0) ----
    short8_t kfh[2], kfl[2];
    short8_t bst[4];
    {
        int coln = kbase + colL;
#pragma unroll
        for (int ch = 0; ch < 2; ch++) {
            size_t off = (size_t)coln * KEYD + ch * 32 + quad * 8;
            kfh[ch] = *(const short8_t*)(kh + off);
            kfl[ch] = *(const short8_t*)(kl + off);
        }
#pragma unroll
        for (int p = 0; p < 4; p++) {
            int idx = t + p * 256;            // 0..1023
            int c = idx >> 3, kk = (idx & 7) * 8;
            bst[p] = *(const short8_t*)(msgTb + (size_t)c * N_AGENTS + kbase + kk);
        }
    }
    float4_t acc[4];
#pragma unroll
    for (int r = 0; r < 4; r++) acc[r] = (float4_t)0.f;
#pragma unroll
    for (int ch = 0; ch < 2; ch++)
#pragma unroll
        for (int r = 0; r < 4; r++) {
            acc[r] = __builtin_amdgcn_mfma_f32_16x16x32_bf16(ah[r][ch], kfh[ch], acc[r], 0, 0, 0);
            acc[r] = __builtin_amdgcn_mfma_f32_16x16x32_bf16(ah[r][ch], kfl[ch], acc[r], 0, 0, 0);
            acc[r] = __builtin_amdgcn_mfma_f32_16x16x32_bf16(al[r][ch], kfh[ch], acc[r], 0, 0, 0);
        }

    __syncthreads();   // inv_s ready

    float vinv[4][4];
#pragma unroll
    for (int r = 0; r < 4; r++)
#pragma unroll
        for (int reg = 0; reg < 4; reg++)
            vinv[r][reg] = inv_s[r * 16 + quad * 4 + reg];

    float pv[4][4];

    for (int st = 0; st < NSTEP; st++) {
        int buf = st & 1;
        int kpos = kbase + st * 64;

        // ---- epilogue(st): normalize -> pv regs + A_lds[buf] ----
#pragma unroll
        for (int r = 0; r < 4; r++)
#pragma unroll
            for (int reg = 0; reg < 4; reg++) {
                int row = r * 16 + quad * 4 + reg;
                int gi = i0 + row;
                float s = acc[r][reg] * 0.125f;
                s = fminf(fmaxf(s, -20.f), 20.f);
                int gj = kpos + colL;
                float p = (gi == gj) ? 0.f : __expf(s) * vinv[r][reg];
                pv[r][reg] = p;
                A_lds[buf][row][colL] = f2bf(p);
            }

        // ---- bst(st) -> B_lds[buf] ----
#pragma unroll
        for (int p = 0; p < 4; p++) {
            int idx = t + p * 256;
            int c = idx >> 3, kk = (idx & 7) * 8;
            *(short8_t*)&B_lds[buf][c][kk] = bst[p];
        }

        __syncthreads();   // A/B[buf] ready; prev-buf readers already fenced

        // ---- P stores: retire under PV + next score ----
#pragma unroll
        for (int r = 0; r < 4; r++)
#pragma unroll
            for (int reg = 0; reg < 4; reg++) {
                int gi = i0 + r * 16 + quad * 4 + reg;
                __builtin_nontemporal_store(pv[r][reg], &P[(size_t)gi * N_AGENTS + kpos + colL]);
            }

        // ---- prefetch step st+1 (K-frags + msgT) ----
        if (st + 1 < NSTEP) {
            int kp2 = kpos + 64;
            int coln = kp2 + colL;
#pragma unroll
            for (int ch = 0; ch < 2; ch++) {
                size_t off = (size_t)coln * KEYD + ch * 32 + quad * 8;
                kfh[ch] = *(const short8_t*)(kh + off);
                kfl[ch] = *(const short8_t*)(kl + off);
            }
#pragma unroll
            for (int p = 0; p < 4; p++) {
                int idx = t + p * 256;
                int c = idx >> 3, kk = (idx & 7) * 8;
                bst[p] = *(const short8_t*)(msgTb + (size_t)c * N_AGENTS + kp2 + kk);
            }
        }

        // ---- PV(st): accm += P_tile @ msgT_tile (k=64) ----
#pragma unroll
        for (int kc = 0; kc < 2; kc++) {
            short8_t a = *(short8_t*)&A_lds[buf][wave * 16 + ln][kc * 32 + quad * 8];
#pragma unroll
            for (int c = 0; c < 8; c++) {
                short8_t b = *(short8_t*)&B_lds[buf][c * 16 + ln][kc * 32 + quad * 8];
                accm[c] = __builtin_amdgcn_mfma_f32_16x16x32_bf16(a, b, accm[c], 0, 0, 0);
            }
        }

        // ---- score(st+1) from prefetched regs ----
        if (st + 1 < NSTEP) {
#pragma unroll
            for (int r = 0; r < 4; r++) acc[r] = (float4_t)0.f;
#pragma unroll
            for (int ch = 0; ch < 2; ch++)
#pragma unroll
                for (int r = 0; r < 4; r++) {
                    acc[r] = __builtin_amdgcn_mfma_f32_16x16x32_bf16(ah[r][ch], kfh[ch], acc[r], 0, 0, 0);
                    acc[r] = __builtin_amdgcn_mfma_f32_16x16x32_bf16(ah[r][ch], kfl[ch], acc[r], 0, 0, 0);
                    acc[r] = __builtin_amdgcn_mfma_f32_16x16x32_bf16(al[r][ch], kfh[ch], acc[r], 0, 0, 0);
                }
        }
    }

    // ---- per-slice partial output (block owns these rows; no atomics) ----
    float* ap = att_part + (size_t)blockIdx.x * N_AGENTS * MSG;
#pragma unroll
    for (int c = 0; c < 8; c++)
#pragma unroll
        for (int reg = 0; reg < 4; reg++) {
            int row = i0 + wave * 16 + quad * 4 + reg;
            int col = c * 16 + ln;
            ap[(size_t)row * MSG + col] = accm[c][reg];
        }
}

// ---------------- Kernel D: GRU cell via MFMA (hi/lo x hi/lo) -----------------
__global__ __launch_bounds__(256) void gru_mfma_kernel(
    const float* __restrict__ att_part, const float* __restrict__ h,
    const short* __restrict__ wT,
    const float* __restrict__ bir, const float* __restrict__ biz,
    const float* __restrict__ bin, const float* __restrict__ bhn,
    float* __restrict__ hnew)
{
    __shared__ short ath[16][136], atl[16][136];  // att hi/lo
    __shared__ short hh[16][264], hl[16][264];    // h hi/lo
    int t = threadIdx.x;
    int wave = t >> 6, l = t & 63, quad = l >> 4, ln = l & 15;
    int i0 = blockIdx.x * 16;
    int cb = wave * 64;

    // stage att (16 x 128 f32) = sum of CSPLIT partial slices
#pragma unroll
    for (int p = 0; p < 2; p++) {
        int idx = t + p * 256;           // 0..511 float4s
        int r = idx >> 5, c4 = (idx & 31) * 4;
        size_t off = (size_t)(i0 + r) * MSG + c4;
        float4 v = *(const float4*)&att_part[off];
#pragma unroll
        for (int s = 1; s < CSPLIT; s++) {
            float4 w = *(const float4*)&att_part[(size_t)s * N_AGENTS * MSG + off];
            v.x += w.x; v.y += w.y; v.z += w.z; v.w += w.w;
        }
        short4_t hv, lv;
        split4(v, &hv, &lv);
        *(short4_t*)&ath[r][c4] = hv;
        *(short4_t*)&atl[r][c4] = lv;
    }
    // stage h (16 x 256 f32)
#pragma unroll
    for (int p = 0; p < 4; p++) {
        int idx = t + p * 256;           // 0..1023 float4s
        int r = idx >> 6, k4 = (idx & 63) * 4;
        float4 v = *(const float4*)&h[(size_t)(i0 + r) * HIDDEN + k4];
        short4_t hv, lv;
        split4(v, &hv, &lv);
        *(short4_t*)&hh[r][k4] = hv;
        *(short4_t*)&hl[r][k4] = lv;
    }
    __syncthreads();

    float4_t ar[4], az[4], an[4], hn[4];
#pragma unroll
    for (int nt = 0; nt < 4; nt++) {
        ar[nt] = (float4_t)0.f; az[nt] = (float4_t)0.f;
        an[nt] = (float4_t)0.f; hn[nt] = (float4_t)0.f;
    }

#define MFMA3(ACC, AH, AL, BH, BL)                                              \
    ACC = __builtin_amdgcn_mfma_f32_16x16x32_bf16(AH, BH, ACC, 0, 0, 0);        \
    ACC = __builtin_amdgcn_mfma_f32_16x16x32_bf16(AH, BL, ACC, 0, 0, 0);        \
    ACC = __builtin_amdgcn_mfma_f32_16x16x32_bf16(AL, BH, ACC, 0, 0, 0);

    // att @ Wi_{r,z,n} : K = 128, 4 chunks
    for (int ch = 0; ch < 4; ch++) {
        short8_t a_h = *(short8_t*)&ath[ln][ch * 32 + quad * 8];
        short8_t a_l = *(short8_t*)&atl[ln][ch * 32 + quad * 8];
#pragma unroll
        for (int nt = 0; nt < 4; nt++) {
            size_t cw = (size_t)(cb + nt * 16 + ln) * 128 + ch * 32 + quad * 8;
            short8_t brh = *(const short8_t*)(wT + OFF_WIR_H + cw);
            short8_t brl = *(const short8_t*)(wT + OFF_WIR_L + cw);
            MFMA3(ar[nt], a_h, a_l, brh, brl);
            short8_t bzh = *(const short8_t*)(wT + OFF_WIZ_H + cw);
            short8_t bzl = *(const short8_t*)(wT + OFF_WIZ_L + cw);
            MFMA3(az[nt], a_h, a_l, bzh, bzl);
            short8_t bnh = *(const short8_t*)(wT + OFF_WIN_H + cw);
            short8_t bnl = *(const short8_t*)(wT + OFF_WIN_L + cw);
            MFMA3(an[nt], a_h, a_l, bnh, bnl);
        }
    }

    // h @ Wh_{r,z,n} : K = 256, 8 chunks
    for (int ch = 0; ch < 8; ch++) {
        short8_t a_h = *(short8_t*)&hh[ln][ch * 32 + quad * 8];
        short8_t a_l = *(short8_t*)&hl[ln][ch * 32 + quad * 8];
#pragma unroll
        for (int nt = 0; nt < 4; nt++) {
            size_t cw = (size_t)(cb + nt * 16 + ln) * 256 + ch * 32 + quad * 8;
            short8_t brh = *(const short8_t*)(wT + OFF_WHR_H + cw);
            short8_t brl = *(const short8_t*)(wT + OFF_WHR_L + cw);
            MFMA3(ar[nt], a_h, a_l, brh, brl);
            short8_t bzh = *(const short8_t*)(wT + OFF_WHZ_H + cw);
            short8_t bzl = *(const short8_t*)(wT + OFF_WHZ_L + cw);
            MFMA3(az[nt], a_h, a_l, bzh, bzl);
            short8_t bnh = *(const short8_t*)(wT + OFF_WHN_H + cw);
            short8_t bnl = *(const short8_t*)(wT + OFF_WHN_L + cw);
            MFMA3(hn[nt], a_h, a_l, bnh, bnl);
        }
    }
#undef MFMA3

    // epilogue: gates + blend (fp32)
#pragma unroll
    for (int nt = 0; nt < 4; nt++) {
        int col = cb + nt * 16 + ln;
        float br = bir[col], bz = biz[col], bn = bin[col], bh_ = bhn[col];
#pragma unroll
        for (int reg = 0; reg < 4; reg++) {
            int row = i0 + quad * 4 + reg;
            float hv = h[(size_t)row * HIDDEN + col];
            float rr = 1.f / (1.f + __expf(-(ar[nt][reg] + br)));
            float zz = 1.f / (1.f + __expf(-(az[nt][reg] + bz)));
            float cand = tanhf(an[nt][reg] + bn + rr * (hn[nt][reg] + bh_));
            hnew[(size_t)row * HIDDEN + col] = (1.f - zz) * cand + zz * hv;
        }
    }
}

// ---------------- launch ------------------------------------------------------
extern "C" void kernel_launch(void* const* d_in, const int* in_sizes, int n_in,
                              void* d_out, int out_size, void* d_ws, size_t ws_size,
                              hipStream_t stream)
{
    const float* h     = (const float*)d_in[0];
    const float* W_msg = (const float*)d_in[1];
    const float* b_msg = (const float*)d_in[2];
    const float* W_key = (const float*)d_in[3];
    const float* b_key = (const float*)d_in[4];
    const float* W_qry = (const float*)d_in[5];
    const float* b_qry = (const float*)d_in[6];
    const float* Wi_r  = (const float*)d_in[7];
    const float* bi_r  = (const float*)d_in[8];
    const float* Wi_z  = (const float*)d_in[9];
    const float* bi_z  = (const float*)d_in[10];
    const float* Wi_n  = (const float*)d_in[11];
    const float* bi_n  = (const float*)d_in[12];
    const float* Wh_r  = (const float*)d_in[13];
    const float* Wh_z  = (const float*)d_in[14];
    const float* Wh_n  = (const float*)d_in[15];
    const float* bh_n  = (const float*)d_in[16];

    float* out  = (float*)d_out;
    float* hnew = out;                                   // [8192,256]
    float* P    = out + (size_t)N_AGENTS * HIDDEN;       // attn region [8192,8192]

    float* ws          = (float*)d_ws;
    float* rowsum_part = ws;                               // 8192*128 f32 (4 MB)
    float* att_part    = ws + (size_t)N_AGENTS * 128;      // CSPLIT * 8192*128 f32
    short* sbase       = (short*)(att_part + (size_t)CSPLIT * N_AGENTS * MSG);
    short* msgTb       = sbase;                            // 128*8192 bf16
    short* qh          = msgTb + (size_t)MSG * N_AGENTS;   // 8192*64
    short* ql          = qh + (size_t)N_AGENTS * KEYD;
    short* kh          = ql + (size_t)N_AGENTS * KEYD;
    short* kl          = kh + (size_t)N_AGENTS * KEYD;
    short* wT          = kl + (size_t)N_AGENTS * KEYD;     // 720896 shorts

    prep_weights<<<1408, 256, 0, stream>>>(W_msg, W_key, W_qry, Wi_r, Wi_z, Wi_n,
                                           Wh_r, Wh_z, Wh_n, wT);

    proj_mfma_kernel<<<N_AGENTS / 16, 256, 0, stream>>>(h, wT, b_msg, b_key, b_qry,
                                                        msgTb, qh, ql, kh, kl);

    rowsum_kernel<<<dim3(N_AGENTS / 256, N_AGENTS / 64), 256, 0, stream>>>(qh, ql, kh, kl,
                                                                           rowsum_part);

    attend_fused_kernel<<<dim3(CSPLIT, N_AGENTS / 64), 256, 0, stream>>>(qh, ql, kh, kl,
                                                                         msgTb, rowsum_part,
                                                                         P, att_part);

    gru_mfma_kernel<<<N_AGENTS / 16, 256, 0, stream>>>(att_part, h, wT, bi_r, bi_z, bi_n, bh_n, hnew);
}

// Round 6
// 522.864 us; speedup vs baseline: 1.6010x; 1.0103x over previous
//
#include <hip/hip_runtime.h>
#include <math.h>

#define N_AGENTS 8192
#define HIDDEN   256
#define MSG      128
#define KEYD     64
#define CSPLIT   4
#define NSTEP    (N_AGENTS / CSPLIT / 64)   // 32

// ---- transposed hi/lo bf16 weight cache layout (shorts, in workspace) -------
#define OFF_WM_H   0        // [128][256]
#define OFF_WM_L   32768
#define OFF_WK_H   65536    // [64][256]
#define OFF_WK_L   81920
#define OFF_WQ_H   98304
#define OFF_WQ_L   114688
#define OFF_WIR_H  131072   // [256][128]
#define OFF_WIR_L  163840
#define OFF_WIZ_H  196608
#define OFF_WIZ_L  229376
#define OFF_WIN_H  262144
#define OFF_WIN_L  294912
#define OFF_WHR_H  327680   // [256][256]
#define OFF_WHR_L  393216
#define OFF_WHZ_H  458752
#define OFF_WHZ_L  524288
#define OFF_WHN_H  589824
#define OFF_WHN_L  655360
#define WT_TOTAL   720896

typedef __attribute__((ext_vector_type(8))) short short8_t;
typedef __attribute__((ext_vector_type(4))) short short4_t;
typedef __attribute__((ext_vector_type(4))) float float4_t;

__device__ __forceinline__ short f2bf(float x) {
    unsigned u = __float_as_uint(x);
    unsigned r = (u + 0x7fffu + ((u >> 16) & 1u)) >> 16;
    return (short)r;
}
__device__ __forceinline__ float bf2f(short b) {
    return __uint_as_float(((unsigned)(unsigned short)b) << 16);
}
__device__ __forceinline__ void split4(float4 v, short4_t* hi, short4_t* lo) {
    (*hi)[0] = f2bf(v.x); (*lo)[0] = f2bf(v.x - bf2f((*hi)[0]));
    (*hi)[1] = f2bf(v.y); (*lo)[1] = f2bf(v.y - bf2f((*hi)[1]));
    (*hi)[2] = f2bf(v.z); (*lo)[2] = f2bf(v.z - bf2f((*hi)[2]));
    (*hi)[3] = f2bf(v.w); (*lo)[3] = f2bf(v.w - bf2f((*hi)[3]));
}

// LDS-only barrier: no vmcnt(0) drain (P stores / prefetch loads stay in
// flight; compiler inserts vmcnt waits at register use). sched_barrier pins
// post-barrier LDS reads (rule: inline-asm waitcnt needs a scheduling fence).
__device__ __forceinline__ void bar_lds() {
    asm volatile("s_waitcnt lgkmcnt(0)" ::: "memory");
    __builtin_amdgcn_s_barrier();
    __builtin_amdgcn_sched_barrier(0);
}

// ---------- Kernel P0: weights -> transposed hi/lo bf16 (runs once) -----------
__global__ __launch_bounds__(256) void prep_weights(
    const float* __restrict__ Wm, const float* __restrict__ Wk, const float* __restrict__ Wq,
    const float* __restrict__ Wir, const float* __restrict__ Wiz, const float* __restrict__ Win,
    const float* __restrict__ Whr, const float* __restrict__ Whz, const float* __restrict__ Whn,
    short* __restrict__ wT)
{
    int idx = blockIdx.x * 256 + threadIdx.x;   // 0..360447
    const float* src; int K, lgC, local; size_t oh, ol;
    if (idx < 32768)        { src = Wm;  K = 256; lgC = 7; local = idx;          oh = OFF_WM_H;  ol = OFF_WM_L; }
    else if (idx < 49152)   { src = Wk;  K = 256; lgC = 6; local = idx - 32768;  oh = OFF_WK_H;  ol = OFF_WK_L; }
    else if (idx < 65536)   { src = Wq;  K = 256; lgC = 6; local = idx - 49152;  oh = OFF_WQ_H;  ol = OFF_WQ_L; }
    else if (idx < 98304)   { src = Wir; K = 128; lgC = 8; local = idx - 65536;  oh = OFF_WIR_H; ol = OFF_WIR_L; }
    else if (idx < 131072)  { src = Wiz; K = 128; lgC = 8; local = idx - 98304;  oh = OFF_WIZ_H; ol = OFF_WIZ_L; }
    else if (idx < 163840)  { src = Win; K = 128; lgC = 8; local = idx - 131072; oh = OFF_WIN_H; ol = OFF_WIN_L; }
    else if (idx < 229376)  { src = Whr; K = 256; lgC = 8; local = idx - 163840; oh = OFF_WHR_H; ol = OFF_WHR_L; }
    else if (idx < 294912)  { src = Whz; K = 256; lgC = 8; local = idx - 229376; oh = OFF_WHZ_H; ol = OFF_WHZ_L; }
    else if (idx < 360448)  { src = Whn; K = 256; lgC = 8; local = idx - 294912; oh = OFF_WHN_H; ol = OFF_WHN_L; }
    else return;
    int k = local >> lgC, c = local & ((1 << lgC) - 1);   // src row-major [k][c]
    float v = src[local];
    short hi = f2bf(v);
    short lo = f2bf(v - bf2f(hi));
    wT[oh + (size_t)c * K + k] = hi;
    wT[ol + (size_t)c * K + k] = lo;
}

// ---------------- Kernel A: projections via MFMA (hi/lo x hi/lo) --------------
__global__ __launch_bounds__(256) void proj_mfma_kernel(
    const float* __restrict__ h, const short* __restrict__ wT,
    const float* __restrict__ bm, const float* __restrict__ bk, const float* __restrict__ bq,
    short* __restrict__ msgTb,
    short* __restrict__ qh, short* __restrict__ ql,
    short* __restrict__ kh, short* __restrict__ kl)
{
    __shared__ short hh[16][264], hl[16][264];   // +8 pad
    int t = threadIdx.x;
    int wave = t >> 6, l = t & 63, quad = l >> 4, ln = l & 15;
    int i0 = blockIdx.x * 16;

#pragma unroll
    for (int p = 0; p < 4; p++) {
        int idx = t + p * 256;           // 0..1023 float4s
        int r = idx >> 6, k4 = (idx & 63) * 4;
        float4 v = *(const float4*)&h[(size_t)(i0 + r) * HIDDEN + k4];
        short4_t hv, lv;
        split4(v, &hv, &lv);
        *(short4_t*)&hh[r][k4] = hv;
        *(short4_t*)&hl[r][k4] = lv;
    }
    __syncthreads();

    size_t base_h, base_l; int cb;
    if (wave < 2)      { base_h = OFF_WM_H; base_l = OFF_WM_L; cb = wave * 64; }
    else if (wave == 2){ base_h = OFF_WK_H; base_l = OFF_WK_L; cb = 0; }
    else               { base_h = OFF_WQ_H; base_l = OFF_WQ_L; cb = 0; }

    float4_t acc[4];
#pragma unroll
    for (int nt = 0; nt < 4; nt++) acc[nt] = (float4_t)0.f;

    for (int ch = 0; ch < 8; ch++) {
        short8_t a_h = *(short8_t*)&hh[ln][ch * 32 + quad * 8];
        short8_t a_l = *(short8_t*)&hl[ln][ch * 32 + quad * 8];
#pragma unroll
        for (int nt = 0; nt < 4; nt++) {
            int c = cb + nt * 16 + ln;
            short8_t b_h = *(const short8_t*)(wT + base_h + (size_t)c * 256 + ch * 32 + quad * 8);
            short8_t b_l = *(const short8_t*)(wT + base_l + (size_t)c * 256 + ch * 32 + quad * 8);
            acc[nt] = __builtin_amdgcn_mfma_f32_16x16x32_bf16(a_h, b_h, acc[nt], 0, 0, 0);
            acc[nt] = __builtin_amdgcn_mfma_f32_16x16x32_bf16(a_h, b_l, acc[nt], 0, 0, 0);
            acc[nt] = __builtin_amdgcn_mfma_f32_16x16x32_bf16(a_l, b_h, acc[nt], 0, 0, 0);
        }
    }

    if (wave < 2) {
#pragma unroll
        for (int nt = 0; nt < 4; nt++) {
            int col = cb + nt * 16 + ln;
            float b = bm[col];
            short4_t o;
#pragma unroll
            for (int reg = 0; reg < 4; reg++) o[reg] = f2bf(acc[nt][reg] + b);
            *(short4_t*)&msgTb[(size_t)col * N_AGENTS + i0 + quad * 4] = o;
        }
    } else {
        short* dh = (wave == 2) ? kh : qh;
        short* dl = (wave == 2) ? kl : ql;
        const float* bias = (wave == 2) ? bk : bq;
#pragma unroll
        for (int nt = 0; nt < 4; nt++) {
            int col = nt * 16 + ln;
            float b = bias[col];
#pragma unroll
            for (int reg = 0; reg < 4; reg++) {
                int row = i0 + quad * 4 + reg;
                float v = acc[nt][reg] + b;
                short hi = f2bf(v);
                short lo = f2bf(v - bf2f(hi));
                dh[(size_t)row * KEYD + col] = hi;
                dl[(size_t)row * KEYD + col] = lo;
            }
        }
    }
}

// ---------- Kernel B1: MFMA scores -> exp -> partial row sums (no atomics) ----
__global__ __launch_bounds__(256) void rowsum_kernel(
    const short* __restrict__ qh, const short* __restrict__ ql,
    const short* __restrict__ kh, const short* __restrict__ kl,
    float* __restrict__ rowsum_part)
{
    int t = threadIdx.x;
    int wave = t >> 6, l = t & 63;
    int quad = l >> 4, ln = l & 15;
    int i0 = blockIdx.y * 64;
    int j0 = blockIdx.x * 256 + wave * 64;

    short8_t ah[4][2], al[4][2];
#pragma unroll
    for (int r = 0; r < 4; r++)
#pragma unroll
        for (int ch = 0; ch < 2; ch++) {
            size_t off = (size_t)(i0 + r * 16 + ln) * KEYD + ch * 32 + quad * 8;
            ah[r][ch] = *(const short8_t*)(qh + off);
            al[r][ch] = *(const short8_t*)(ql + off);
        }

    float4_t acc[4][4];
#pragma unroll
    for (int r = 0; r < 4; r++)
#pragma unroll
        for (int c = 0; c < 4; c++) acc[r][c] = (float4_t)0.f;

#pragma unroll
    for (int c = 0; c < 4; c++) {
        int coln = j0 + c * 16 + ln;
#pragma unroll
        for (int ch = 0; ch < 2; ch++) {
            size_t off = (size_t)coln * KEYD + ch * 32 + quad * 8;
            short8_t bh = *(const short8_t*)(kh + off);
            short8_t bl = *(const short8_t*)(kl + off);
#pragma unroll
            for (int r = 0; r < 4; r++) {
                acc[r][c] = __builtin_amdgcn_mfma_f32_16x16x32_bf16(ah[r][ch], bh, acc[r][c], 0, 0, 0);
                acc[r][c] = __builtin_amdgcn_mfma_f32_16x16x32_bf16(ah[r][ch], bl, acc[r][c], 0, 0, 0);
                acc[r][c] = __builtin_amdgcn_mfma_f32_16x16x32_bf16(al[r][ch], bh, acc[r][c], 0, 0, 0);
            }
        }
    }

    float prow[4][4];
#pragma unroll
    for (int r = 0; r < 4; r++)
#pragma unroll
        for (int reg = 0; reg < 4; reg++) {
            int gi = i0 + r * 16 + quad * 4 + reg;
            float sum = 0.f;
#pragma unroll
            for (int c = 0; c < 4; c++) {
                float s = acc[r][c][reg] * 0.125f;
                s = fminf(fmaxf(s, -20.f), 20.f);
                int gj = j0 + c * 16 + ln;
                float p = (gi == gj) ? 0.f : __expf(s);
                sum += p;
            }
            prow[r][reg] = sum;
        }

#pragma unroll
    for (int off = 1; off < 16; off <<= 1)
#pragma unroll
        for (int r = 0; r < 4; r++)
#pragma unroll
            for (int reg = 0; reg < 4; reg++)
                prow[r][reg] += __shfl_xor(prow[r][reg], off);

    if (ln == 0) {
        int pidx = blockIdx.x * 4 + wave;
#pragma unroll
        for (int r = 0; r < 4; r++)
#pragma unroll
            for (int reg = 0; reg < 4; reg++)
                rowsum_part[(size_t)(i0 + r * 16 + quad * 4 + reg) * 128 + pidx] = prow[r][reg];
    }
}

// ---- Kernel B2: 1-barrier/step double-buffered fused score+P-write+PV --------
// In-loop barrier is LDS-only (bar_lds): P stores and prefetch loads stay in
// flight across it — removes the per-step vmcnt(0) store-drain stall.
__global__ __launch_bounds__(256, 2) void attend_fused_kernel(
    const short* __restrict__ qh, const short* __restrict__ ql,
    const short* __restrict__ kh, const short* __restrict__ kl,
    const short* __restrict__ msgTb, const float* __restrict__ rowsum_part,
    float* __restrict__ P, float* __restrict__ att_part)
{
    __shared__ short A_lds[2][64][72];    // P tile bf16, dbuf
    __shared__ short B_lds[2][128][72];   // msgT tile, dbuf
    __shared__ float inv_s[64];

    int t = threadIdx.x;
    int wave = t >> 6, l = t & 63;
    int quad = l >> 4, ln = l & 15;
    int i0 = blockIdx.y * 64;
    int kbase = blockIdx.x * (N_AGENTS / CSPLIT);

    // 1/rowsum from 128 partials
    if (t < 64) {
        const float* rp = rowsum_part + (size_t)(i0 + t) * 128;
        float s = 0.f;
#pragma unroll
        for (int p = 0; p < 32; p++) {
            float4 v = *(const float4*)(rp + p * 4);
            s += v.x + v.y + v.z + v.w;
        }
        inv_s[t] = 1.0f / s;
    }

    // Q fragments (persist all steps)
    short8_t ah[4][2], al[4][2];
#pragma unroll
    for (int r = 0; r < 4; r++)
#pragma unroll
        for (int ch = 0; ch < 2; ch++) {
            size_t off = (size_t)(i0 + r * 16 + ln) * KEYD + ch * 32 + quad * 8;
            ah[r][ch] = *(const short8_t*)(qh + off);
            al[r][ch] = *(const short8_t*)(ql + off);
        }

    float4_t accm[8];
#pragma unroll
    for (int c = 0; c < 8; c++) accm[c] = (float4_t)0.f;

    const int colL = wave * 16 + ln;

    // ---- prologue: load step-0 K-frags + msgT, compute score(0) ----
    short8_t kfh[2], kfl[2];
    short8_t bst[4];
    {
        int coln = kbase + colL;
#pragma unroll
        for (int ch = 0; ch < 2; ch++) {
            size_t off = (size_t)coln * KEYD + ch * 32 + quad * 8;
            kfh[ch] = *(const short8_t*)(kh + off);
            kfl[ch] = *(const short8_t*)(kl + off);
        }
#pragma unroll
        for (int p = 0; p < 4; p++) {
            int idx = t + p * 256;            // 0..1023
            int c = idx >> 3, kk = (idx & 7) * 8;
            bst[p] = *(const short8_t*)(msgTb + (size_t)c * N_AGENTS + kbase + kk);
        }
    }
    float4_t acc[4];
#pragma unroll
    for (int r = 0; r < 4; r++) acc[r] = (float4_t)0.f;
#pragma unroll
    for (int ch = 0; ch < 2; ch++)
#pragma unroll
        for (int r = 0; r < 4; r++) {
            acc[r] = __builtin_amdgcn_mfma_f32_16x16x32_bf16(ah[r][ch], kfh[ch], acc[r], 0, 0, 0);
            acc[r] = __builtin_amdgcn_mfma_f32_16x16x32_bf16(ah[r][ch], kfl[ch], acc[r], 0, 0, 0);
            acc[r] = __builtin_amdgcn_mfma_f32_16x16x32_bf16(al[r][ch], kfh[ch], acc[r], 0, 0, 0);
        }

    __syncthreads();   // inv_s ready (full barrier once)

    float vinv[4][4];
#pragma unroll
    for (int r = 0; r < 4; r++)
#pragma unroll
        for (int reg = 0; reg < 4; reg++)
            vinv[r][reg] = inv_s[r * 16 + quad * 4 + reg];

    float pv[4][4];

    for (int st = 0; st < NSTEP; st++) {
        int buf = st & 1;
        int kpos = kbase + st * 64;

        // ---- epilogue(st): normalize -> pv regs + A_lds[buf] ----
#pragma unroll
        for (int r = 0; r < 4; r++)
#pragma unroll
            for (int reg = 0; reg < 4; reg++) {
                int row = r * 16 + quad * 4 + reg;
                int gi = i0 + row;
                float s = acc[r][reg] * 0.125f;
                s = fminf(fmaxf(s, -20.f), 20.f);
                int gj = kpos + colL;
                float p = (gi == gj) ? 0.f : __expf(s) * vinv[r][reg];
                pv[r][reg] = p;
                A_lds[buf][row][colL] = f2bf(p);
            }

        // ---- bst(st) -> B_lds[buf] ----
#pragma unroll
        for (int p = 0; p < 4; p++) {
            int idx = t + p * 256;
            int c = idx >> 3, kk = (idx & 7) * 8;
            *(short8_t*)&B_lds[buf][c][kk] = bst[p];
        }

        bar_lds();   // LDS-only: A/B[buf] visible; vmem stays in flight

        // ---- P stores: fire-and-forget (never drained in-loop) ----
#pragma unroll
        for (int r = 0; r < 4; r++)
#pragma unroll
            for (int reg = 0; reg < 4; reg++) {
                int gi = i0 + r * 16 + quad * 4 + reg;
                __builtin_nontemporal_store(pv[r][reg], &P[(size_t)gi * N_AGENTS + kpos + colL]);
            }

        // ---- prefetch step st+1 (K-frags + msgT) ----
        if (st + 1 < NSTEP) {
            int kp2 = kpos + 64;
            int coln = kp2 + colL;
#pragma unroll
            for (int ch = 0; ch < 2; ch++) {
                size_t off = (size_t)coln * KEYD + ch * 32 + quad * 8;
                kfh[ch] = *(const short8_t*)(kh + off);
                kfl[ch] = *(const short8_t*)(kl + off);
            }
#pragma unroll
            for (int p = 0; p < 4; p++) {
                int idx = t + p * 256;
                int c = idx >> 3, kk = (idx & 7) * 8;
                bst[p] = *(const short8_t*)(msgTb + (size_t)c * N_AGENTS + kp2 + kk);
            }
        }

        // ---- PV(st): accm += P_tile @ msgT_tile (k=64) ----
#pragma unroll
        for (int kc = 0; kc < 2; kc++) {
            short8_t a = *(short8_t*)&A_lds[buf][wave * 16 + ln][kc * 32 + quad * 8];
#pragma unroll
            for (int c = 0; c < 8; c++) {
                short8_t b = *(short8_t*)&B_lds[buf][c * 16 + ln][kc * 32 + quad * 8];
                accm[c] = __builtin_amdgcn_mfma_f32_16x16x32_bf16(a, b, accm[c], 0, 0, 0);
            }
        }

        // ---- score(st+1) from prefetched regs ----
        if (st + 1 < NSTEP) {
#pragma unroll
            for (int r = 0; r < 4; r++) acc[r] = (float4_t)0.f;
#pragma unroll
            for (int ch = 0; ch < 2; ch++)
#pragma unroll
                for (int r = 0; r < 4; r++) {
                    acc[r] = __builtin_amdgcn_mfma_f32_16x16x32_bf16(ah[r][ch], kfh[ch], acc[r], 0, 0, 0);
                    acc[r] = __builtin_amdgcn_mfma_f32_16x16x32_bf16(ah[r][ch], kfl[ch], acc[r], 0, 0, 0);
                    acc[r] = __builtin_amdgcn_mfma_f32_16x16x32_bf16(al[r][ch], kfh[ch], acc[r], 0, 0, 0);
                }
        }
    }

    // ---- per-slice partial output (block owns these rows; no atomics) ----
    float* ap = att_part + (size_t)blockIdx.x * N_AGENTS * MSG;
#pragma unroll
    for (int c = 0; c < 8; c++)
#pragma unroll
        for (int reg = 0; reg < 4; reg++) {
            int row = i0 + wave * 16 + quad * 4 + reg;
            int col = c * 16 + ln;
            ap[(size_t)row * MSG + col] = accm[c][reg];
        }
}

// ---------------- Kernel D: GRU cell via MFMA, R=32 / 512 threads -------------
// 256 blocks (1/CU) x 32 rows: halves the per-block weight re-read (wT L2
// traffic 737 -> 368 MB). 8 waves: wave = (rowgrp rg in {0,16}) x (colgrp cb).
__global__ __launch_bounds__(512) void gru_mfma_kernel(
    const float* __restrict__ att_part, const float* __restrict__ h,
    const short* __restrict__ wT,
    const float* __restrict__ bir, const float* __restrict__ biz,
    const float* __restrict__ bin, const float* __restrict__ bhn,
    float* __restrict__ hnew)
{
    __shared__ short ath[32][136], atl[32][136];  // att hi/lo
    __shared__ short hh[32][264], hl[32][264];    // h hi/lo
    int t = threadIdx.x;                 // 0..511
    int wave = t >> 6, l = t & 63, quad = l >> 4, ln = l & 15;
    int i0 = blockIdx.x * 32;
    int cb = (wave & 3) * 64;
    int rg = (wave >> 2) * 16;

    // stage att (32 x 128 f32) = sum of CSPLIT partial slices
#pragma unroll
    for (int p = 0; p < 2; p++) {
        int idx = t + p * 512;           // 0..1023 float4s
        int r = idx >> 5, c4 = (idx & 31) * 4;
        size_t off = (size_t)(i0 + r) * MSG + c4;
        float4 v = *(const float4*)&att_part[off];
#pragma unroll
        for (int s = 1; s < CSPLIT; s++) {
            float4 w = *(const float4*)&att_part[(size_t)s * N_AGENTS * MSG + off];
            v.x += w.x; v.y += w.y; v.z += w.z; v.w += w.w;
        }
        short4_t hv, lv;
        split4(v, &hv, &lv);
        *(short4_t*)&ath[r][c4] = hv;
        *(short4_t*)&atl[r][c4] = lv;
    }
    // stage h (32 x 256 f32)
#pragma unroll
    for (int p = 0; p < 4; p++) {
        int idx = t + p * 512;           // 0..2047 float4s
        int r = idx >> 6, k4 = (idx & 63) * 4;
        float4 v = *(const float4*)&h[(size_t)(i0 + r) * HIDDEN + k4];
        short4_t hv, lv;
        split4(v, &hv, &lv);
        *(short4_t*)&hh[r][k4] = hv;
        *(short4_t*)&hl[r][k4] = lv;
    }
    __syncthreads();

    float4_t ar[4], az[4], an[4], hn[4];
#pragma unroll
    for (int nt = 0; nt < 4; nt++) {
        ar[nt] = (float4_t)0.f; az[nt] = (float4_t)0.f;
        an[nt] = (float4_t)0.f; hn[nt] = (float4_t)0.f;
    }

#define MFMA3(ACC, AH, AL, BH, BL)                                              \
    ACC = __builtin_amdgcn_mfma_f32_16x16x32_bf16(AH, BH, ACC, 0, 0, 0);        \
    ACC = __builtin_amdgcn_mfma_f32_16x16x32_bf16(AH, BL, ACC, 0, 0, 0);        \
    ACC = __builtin_amdgcn_mfma_f32_16x16x32_bf16(AL, BH, ACC, 0, 0, 0);

    // att @ Wi_{r,z,n} : K = 128, 4 chunks
    for (int ch = 0; ch < 4; ch++) {
        short8_t a_h = *(short8_t*)&ath[rg + ln][ch * 32 + quad * 8];
        short8_t a_l = *(short8_t*)&atl[rg + ln][ch * 32 + quad * 8];
#pragma unroll
        for (int nt = 0; nt < 4; nt++) {
            size_t cw = (size_t)(cb + nt * 16 + ln) * 128 + ch * 32 + quad * 8;
            short8_t brh = *(const short8_t*)(wT + OFF_WIR_H + cw);
            short8_t brl = *(const short8_t*)(wT + OFF_WIR_L + cw);
            MFMA3(ar[nt], a_h, a_l, brh, brl);
            short8_t bzh = *(const short8_t*)(wT + OFF_WIZ_H + cw);
            short8_t bzl = *(const short8_t*)(wT + OFF_WIZ_L + cw);
            MFMA3(az[nt], a_h, a_l, bzh, bzl);
            short8_t bnh = *(const short8_t*)(wT + OFF_WIN_H + cw);
            short8_t bnl = *(const short8_t*)(wT + OFF_WIN_L + cw);
            MFMA3(an[nt], a_h, a_l, bnh, bnl);
        }
    }

    // h @ Wh_{r,z,n} : K = 256, 8 chunks
    for (int ch = 0; ch < 8; ch++) {
        short8_t a_h = *(short8_t*)&hh[rg + ln][ch * 32 + quad * 8];
        short8_t a_l = *(short8_t*)&hl[rg + ln][ch * 32 + quad * 8];
#pragma unroll
        for (int nt = 0; nt < 4; nt++) {
            size_t cw = (size_t)(cb + nt * 16 + ln) * 256 + ch * 32 + quad * 8;
            short8_t brh = *(const short8_t*)(wT + OFF_WHR_H + cw);
            short8_t brl = *(const short8_t*)(wT + OFF_WHR_L + cw);
            MFMA3(ar[nt], a_h, a_l, brh, brl);
            short8_t bzh = *(const short8_t*)(wT + OFF_WHZ_H + cw);
            short8_t bzl = *(const short8_t*)(wT + OFF_WHZ_L + cw);
            MFMA3(az[nt], a_h, a_l, bzh, bzl);
            short8_t bnh = *(const short8_t*)(wT + OFF_WHN_H + cw);
            short8_t bnl = *(const short8_t*)(wT + OFF_WHN_L + cw);
            MFMA3(hn[nt], a_h, a_l, bnh, bnl);
        }
    }
#undef MFMA3

    // epilogue: gates + blend (fp32)
#pragma unroll
    for (int nt = 0; nt < 4; nt++) {
        int col = cb + nt * 16 + ln;
        float br = bir[col], bz = biz[col], bn = bin[col], bh_ = bhn[col];
#pragma unroll
        for (int reg = 0; reg < 4; reg++) {
            int row = i0 + rg + quad * 4 + reg;
            float hv = h[(size_t)row * HIDDEN + col];
            float rr = 1.f / (1.f + __expf(-(ar[nt][reg] + br)));
            float zz = 1.f / (1.f + __expf(-(az[nt][reg] + bz)));
            float cand = tanhf(an[nt][reg] + bn + rr * (hn[nt][reg] + bh_));
            hnew[(size_t)row * HIDDEN + col] = (1.f - zz) * cand + zz * hv;
        }
    }
}

// ---------------- launch ------------------------------------------------------
extern "C" void kernel_launch(void* const* d_in, const int* in_sizes, int n_in,
                              void* d_out, int out_size, void* d_ws, size_t ws_size,
                              hipStream_t stream)
{
    const float* h     = (const float*)d_in[0];
    const float* W_msg = (const float*)d_in[1];
    const float* b_msg = (const float*)d_in[2];
    const float* W_key = (const float*)d_in[3];
    const float* b_key = (const float*)d_in[4];
    const float* W_qry = (const float*)d_in[5];
    const float* b_qry = (const float*)d_in[6];
    const float* Wi_r  = (const float*)d_in[7];
    const float* bi_r  = (const float*)d_in[8];
    const float* Wi_z  = (const float*)d_in[9];
    const float* bi_z  = (const float*)d_in[10];
    const float* Wi_n  = (const float*)d_in[11];
    const float* bi_n  = (const float*)d_in[12];
    const float* Wh_r  = (const float*)d_in[13];
    const float* Wh_z  = (const float*)d_in[14];
    const float* Wh_n  = (const float*)d_in[15];
    const float* bh_n  = (const float*)d_in[16];

    float* out  = (float*)d_out;
    float* hnew = out;                                   // [8192,256]
    float* P    = out + (size_t)N_AGENTS * HIDDEN;       // attn region [8192,8192]

    float* ws          = (float*)d_ws;
    float* rowsum_part = ws;                               // 8192*128 f32 (4 MB)
    float* att_part    = ws + (size_t)N_AGENTS * 128;      // CSPLIT * 8192*128 f32
    short* sbase       = (short*)(att_part + (size_t)CSPLIT * N_AGENTS * MSG);
    short* msgTb       = sbase;                            // 128*8192 bf16
    short* qh          = msgTb + (size_t)MSG * N_AGENTS;   // 8192*64
    short* ql          = qh + (size_t)N_AGENTS * KEYD;
    short* kh          = ql + (size_t)N_AGENTS * KEYD;
    short* kl          = kh + (size_t)N_AGENTS * KEYD;
    short* wT          = kl + (size_t)N_AGENTS * KEYD;     // 720896 shorts

    prep_weights<<<1408, 256, 0, stream>>>(W_msg, W_key, W_qry, Wi_r, Wi_z, Wi_n,
                                           Wh_r, Wh_z, Wh_n, wT);

    proj_mfma_kernel<<<N_AGENTS / 16, 256, 0, stream>>>(h, wT, b_msg, b_key, b_qry,
                                                        msgTb, qh, ql, kh, kl);

    rowsum_kernel<<<dim3(N_AGENTS / 256, N_AGENTS / 64), 256, 0, stream>>>(qh, ql, kh, kl,
                                                                           rowsum_part);

    attend_fused_kernel<<<dim3(CSPLIT, N_AGENTS / 64), 256, 0, stream>>>(qh, ql, kh, kl,
                                                                         msgTb, rowsum_part,
                                                                         P, att_part);

    gru_mfma_kernel<<<N_AGENTS / 32, 512, 0, stream>>>(att_part, h, wT, bi_r, bi_z, bi_n, bh_n, hnew);
}